// Round 1
// baseline (306735.229 us; speedup 1.0000x reference)
//
#include <hip/hip_runtime.h>
#include <math.h>

#define ACT_NONE 0
#define ACT_RELU 1
#define ACT_LEAKY 2

__device__ __forceinline__ float actf(float y, int act) {
    if (act == ACT_RELU)  return y > 0.f ? y : 0.f;
    if (act == ACT_LEAKY) return y >= 0.f ? y : 0.2f * y;
    return y;
}

// ---------------------------------------------------------------------------
// Mask convolution: mc = conv(mask_maybe_upsampled, ones(K,K), stride S, pad P)
// Also emits new_mask = (mc != 0).
// ---------------------------------------------------------------------------
template<int K, int S, bool MHALF>
__global__ void maskconv_kernel(const float* __restrict__ M, int HM, int WM,
                                float* __restrict__ mc, float* __restrict__ nm,
                                int N, int Hin, int Win, int Hout, int Wout) {
    constexpr int P = (K - 1) / 2;
    int idx = blockIdx.x * blockDim.x + threadIdx.x;
    int total = N * Hout * Wout;
    if (idx >= total) return;
    int wo = idx % Wout;
    int t  = idx / Wout;
    int ho = t % Hout;
    int n  = t / Hout;
    float s = 0.f;
    for (int kh = 0; kh < K; ++kh) {
        int ih = ho * S - P + kh;
        if ((unsigned)ih >= (unsigned)Hin) continue;
        const float* mrow = M + ((size_t)n * HM + (MHALF ? (ih >> 1) : ih)) * WM;
        for (int kw = 0; kw < K; ++kw) {
            int iw = wo * S - P + kw;
            if ((unsigned)iw < (unsigned)Win)
                s += mrow[MHALF ? (iw >> 1) : iw];
        }
    }
    mc[idx] = s;
    nm[idx] = (s == 0.f) ? 0.f : 1.f;
}

// ---------------------------------------------------------------------------
// Partial convolution: y = conv((A|B) * mask, W, S, pad (K-1)/2), then
// renormalize by mc (with optional bias trick), zero holes, optional act.
// A may be stored at half resolution (UPA -> nearest up2 via index>>1).
// Mask may be stored at half resolution (MHALF).
// Channel order: A's CA channels first, then B's CB channels (concat).
// ---------------------------------------------------------------------------
template<int K, int S, bool UPA, bool MHALF>
__global__ __launch_bounds__(256) void pconv_kernel(
    const float* __restrict__ A, int CA, int HA, int WA,
    const float* __restrict__ B, int CB,
    const float* __restrict__ M, int HM, int WM,
    const float* __restrict__ Wt,
    const float* __restrict__ mc,
    const float* __restrict__ bias,
    float* __restrict__ out,
    int Hin, int Win, int Hout, int Wout, int Cout,
    int act) {
    constexpr int T = 4;
    constexpr int P = (K - 1) / 2;
    constexpr int SPAN = (T - 1) * S + K;
    const int WT = (Wout + T - 1) / T;
    int idx = blockIdx.x * blockDim.x + threadIdx.x;
    if (idx >= Hout * WT) return;
    const int ho  = idx / WT;
    const int wo0 = (idx - ho * WT) * T;
    const int co  = blockIdx.y;
    const int n   = blockIdx.z;
    const int Cin = CA + CB;
    float acc[T] = {0.f, 0.f, 0.f, 0.f};
    const float* wbase = Wt + (size_t)co * Cin * K * K;
    const int iw0 = wo0 * S - P;

    for (int ci = 0; ci < Cin; ++ci) {
        const bool isA = ci < CA;
        for (int kh = 0; kh < K; ++kh) {
            const int ih = ho * S - P + kh;
            if ((unsigned)ih >= (unsigned)Hin) continue;
            const float* mrow = M + ((size_t)n * HM + (MHALF ? (ih >> 1) : ih)) * WM;
            const float* arow;
            if (isA) arow = A + (((size_t)n * CA + ci) * HA + (UPA ? (ih >> 1) : ih)) * WA;
            else     arow = B + (((size_t)n * CB + (ci - CA)) * (size_t)Hin + ih) * Win;
            const float* wrow = wbase + ((size_t)ci * K + kh) * K;
            float xv[SPAN];
#pragma unroll
            for (int u = 0; u < SPAN; ++u) {
                const int iw = iw0 + u;
                float v = 0.f;
                if ((unsigned)iw < (unsigned)Win) {
                    const float mv = mrow[MHALF ? (iw >> 1) : iw];
                    float av;
                    if (isA) av = arow[UPA ? (iw >> 1) : iw];
                    else     av = arow[iw];
                    v = av * mv;
                }
                xv[u] = v;
            }
#pragma unroll
            for (int t = 0; t < T; ++t) {
#pragma unroll
                for (int kw = 0; kw < K; ++kw) {
                    acc[t] = fmaf(xv[t * S + kw], wrow[kw], acc[t]);
                }
            }
        }
    }

    const float* mcrow = mc + ((size_t)n * Hout + ho) * Wout;
    float* orow = out + (((size_t)n * Cout + co) * (size_t)Hout + ho) * Wout;
    const float bv = bias ? bias[co] : 0.f;
#pragma unroll
    for (int t = 0; t < T; ++t) {
        const int wo = wo0 + t;
        if (wo < Wout) {
            const float m = mcrow[wo];
            float y;
            if (m == 0.f) y = 0.f;
            else if (bias) y = (acc[t] - bv) / m + bv;
            else           y = acc[t] / m;
            orow[wo] = actf(y, act);
        }
    }
}

// ---------------------------------------------------------------------------
// BatchNorm (training-mode, biased var over N,H,W)
// ---------------------------------------------------------------------------
__global__ __launch_bounds__(256) void bn_stats_kernel(const float* __restrict__ y,
                                                       int N, int C, int HW,
                                                       float* __restrict__ mean,
                                                       float* __restrict__ istd) {
    const int c = blockIdx.x;
    double s = 0.0, s2 = 0.0;
    const int tot = N * HW;
    for (int i = threadIdx.x; i < tot; i += blockDim.x) {
        int n = i / HW, hw = i - n * HW;
        float v = y[((size_t)n * C + c) * HW + hw];
        s += v;
        s2 += (double)v * v;
    }
    __shared__ double sh[256], sh2[256];
    sh[threadIdx.x] = s; sh2[threadIdx.x] = s2;
    __syncthreads();
    for (int o = 128; o > 0; o >>= 1) {
        if (threadIdx.x < o) { sh[threadIdx.x] += sh[threadIdx.x + o]; sh2[threadIdx.x] += sh2[threadIdx.x + o]; }
        __syncthreads();
    }
    if (threadIdx.x == 0) {
        double mu = sh[0] / tot;
        double var = sh2[0] / tot - mu * mu;
        mean[c] = (float)mu;
        istd[c] = (float)(1.0 / sqrt(var + 1e-5));
    }
}

__global__ void bn_apply_kernel(float* __restrict__ y,
                                const float* __restrict__ mean, const float* __restrict__ istd,
                                const float* __restrict__ g, const float* __restrict__ b,
                                int C, int HW, int total, int act) {
    int idx = blockIdx.x * blockDim.x + threadIdx.x;
    if (idx >= total) return;
    int c = (idx / HW) % C;
    float v = (y[idx] - mean[c]) * istd[c] * g[c] + b[c];
    y[idx] = actf(v, act);
}

// ---------------------------------------------------------------------------
// NLM feature swapping at h2 (B=8, C=512, Npix=1296)
// ---------------------------------------------------------------------------
#define NLM_C 512
#define NLM_N 1296

__global__ void nlm_prep_kernel(const float* __restrict__ h2, float* __restrict__ xT,
                                int Bn, int C, int Npix) {
    size_t idx = (size_t)blockIdx.x * blockDim.x + threadIdx.x;
    size_t total = (size_t)Bn * Npix * C;
    if (idx >= total) return;
    int c = (int)(idx % C);
    size_t t = idx / C;
    int j = (int)(t % Npix);
    int b = (int)(t / Npix);
    xT[idx] = h2[((size_t)b * C + c) * Npix + j];
}

__global__ void nlm_sq_kernel(const float* __restrict__ xT, float* __restrict__ sq,
                              int BN, int C) {
    int idx = blockIdx.x * blockDim.x + threadIdx.x;
    if (idx >= BN) return;
    const float* r = xT + (size_t)idx * C;
    float s = 0.f;
    for (int c = 0; c < C; ++c) s = fmaf(r[c], r[c], s);
    sq[idx] = s;
}

__global__ __launch_bounds__(256) void nlm_kernel(
    const float* __restrict__ xT, const float* __restrict__ sq,
    const float* __restrict__ mask,  // 0/1, [B][Npix]
    float* __restrict__ out,         // h2s, NCHW = [B][C][Npix]
    float inv_h2) {
    const int i = blockIdx.x;
    const int b = blockIdx.y;
    const int tid = threadIdx.x;
    if (mask[(size_t)b * NLM_N + i] > 0.5f) return;  // background: keep copied x

    __shared__ float Drow[NLM_N];
    __shared__ float xi[NLM_C];
    __shared__ float red[256];

    const float* xib = xT + ((size_t)b * NLM_N + i) * NLM_C;
    for (int c = tid; c < NLM_C; c += 256) xi[c] = xib[c];
    __syncthreads();

    const float sqi = sq[(size_t)b * NLM_N + i];
    const float BIG = 3.4e38f;
    float lmin = BIG;
    for (int j = tid; j < NLM_N; j += 256) {
        float d = BIG;
        if (mask[(size_t)b * NLM_N + j] > 0.5f) {
            const float* xj = xT + ((size_t)b * NLM_N + j) * NLM_C;
            float dot = 0.f;
            for (int c = 0; c < NLM_C; ++c) dot = fmaf(xi[c], xj[c], dot);
            d = sqi + sq[(size_t)b * NLM_N + j] - 2.f * dot;
            d = d > 0.f ? d : 0.f;
            lmin = d < lmin ? d : lmin;
        }
        Drow[j] = d;
    }
    red[tid] = lmin;
    __syncthreads();
    for (int o = 128; o > 0; o >>= 1) {
        if (tid < o) red[tid] = fminf(red[tid], red[tid + o]);
        __syncthreads();
    }
    const float dmin = red[0];
    __syncthreads();

    float lsum = 0.f;
    for (int j = tid; j < NLM_N; j += 256) {
        float wv = 0.f;
        if (Drow[j] < 3.3e38f) wv = expf(-(Drow[j] - dmin) * inv_h2);
        Drow[j] = wv;
        lsum += wv;
    }
    red[tid] = lsum;
    __syncthreads();
    for (int o = 128; o > 0; o >>= 1) {
        if (tid < o) red[tid] += red[tid + o];
        __syncthreads();
    }
    const float invw = 1.f / red[0];
    __syncthreads();

    for (int c = tid; c < NLM_C; c += 256) {
        float a = 0.f;
        for (int j = 0; j < NLM_N; ++j)
            a = fmaf(Drow[j], xT[((size_t)b * NLM_N + j) * NLM_C + c], a);
        out[((size_t)b * NLM_C + c) * NLM_N + i] = a * invw;
    }
}

// ---------------------------------------------------------------------------
// Driver
// ---------------------------------------------------------------------------
extern "C" void kernel_launch(void* const* d_in, const int* in_sizes, int n_in,
                              void* d_out, int out_size, void* d_ws, size_t ws_size,
                              hipStream_t stream) {
    const float* x0    = (const float*)d_in[0];
    const float* m0    = (const float*)d_in[1];
    const float* enc1W = (const float*)d_in[2];
    const float* enc2W = (const float*)d_in[3];
    const float* enc3W = (const float*)d_in[4];
    const float* enc4W = (const float*)d_in[5];
    const float* dec4W = (const float*)d_in[6];
    const float* dec3W = (const float*)d_in[7];
    const float* dec2W = (const float*)d_in[8];
    const float* dec1W = (const float*)d_in[9];
    const float* dec1b = (const float*)d_in[10];
    const float* enc2g = (const float*)d_in[11];
    const float* enc2b = (const float*)d_in[12];
    const float* enc3g = (const float*)d_in[13];
    const float* enc3b = (const float*)d_in[14];
    const float* enc4g = (const float*)d_in[15];
    const float* enc4b = (const float*)d_in[16];
    const float* dec4g = (const float*)d_in[17];
    const float* dec4b = (const float*)d_in[18];
    const float* dec3g = (const float*)d_in[19];
    const float* dec3b = (const float*)d_in[20];
    const float* dec2g = (const float*)d_in[21];
    const float* dec2b = (const float*)d_in[22];
    float* outp = (float*)d_out;

    const int N = 8;
    float* ws = (float*)d_ws;
    size_t off = 0;
    auto alloc = [&](size_t nf) {
        size_t o = off;
        off += ((nf + 63) / 64) * 64;
        return ws + o;
    };

    float* h1   = alloc(10616832);  // 8x256x72x72
    float* h2   = alloc(5308416);   // 8x512x36x36
    float* h2s  = alloc(5308416);
    float* xT   = alloc(5308416);
    float* sqb  = alloc(10368);
    float* h3   = alloc(1327104);   // 8x512x18x18
    float* h4   = alloc(331776);    // 8x512x9x9
    float* d4   = alloc(1327104);
    float* d2   = alloc(10616832);  // 8x256x72x72
    float* mc   = alloc(165888);    // shared mask-sum scratch (max 8x144x144)
    float* nm1  = alloc(41472);
    float* nm2  = alloc(10368);
    float* nm3  = alloc(2592);
    float* nm4  = alloc(648);
    float* nmd4 = alloc(2592);
    float* nmd3 = alloc(10368);
    float* nmd2 = alloc(41472);
    float* nmx  = alloc(165888);
    float* bmean = alloc(512);
    float* bistd = alloc(512);
    float* d3 = h2;  // h2 dead after NLM; reuse for dec3 output

    if (ws_size < off * sizeof(float)) return;  // workspace too small; fail loudly

    auto cdiv = [](int a, int b) { return (a + b - 1) / b; };

    // ---------------- enc1: 128->256, 7x7 s2 p3, relu, no BN ----------------
    maskconv_kernel<7, 2, false><<<cdiv(N * 72 * 72, 256), 256, 0, stream>>>(
        m0, 144, 144, mc, nm1, N, 144, 144, 72, 72);
    {
        int HWT = 72 * 18;
        pconv_kernel<7, 2, false, false><<<dim3(cdiv(HWT, 256), 256, N), 256, 0, stream>>>(
            x0, 128, 144, 144, nullptr, 0, m0, 144, 144, enc1W, mc, nullptr,
            h1, 144, 144, 72, 72, 256, ACT_RELU);
    }

    // ---------------- enc2: 256->512, 5x5 s2 p2, BN+relu ----------------
    maskconv_kernel<5, 2, false><<<cdiv(N * 36 * 36, 256), 256, 0, stream>>>(
        nm1, 72, 72, mc, nm2, N, 72, 72, 36, 36);
    {
        int HWT = 36 * 9;
        pconv_kernel<5, 2, false, false><<<dim3(cdiv(HWT, 256), 512, N), 256, 0, stream>>>(
            h1, 256, 72, 72, nullptr, 0, nm1, 72, 72, enc2W, mc, nullptr,
            h2, 72, 72, 36, 36, 512, ACT_NONE);
    }
    bn_stats_kernel<<<512, 256, 0, stream>>>(h2, N, 512, 1296, bmean, bistd);
    bn_apply_kernel<<<cdiv(5308416, 256), 256, 0, stream>>>(h2, bmean, bistd, enc2g, enc2b,
                                                            512, 1296, 5308416, ACT_RELU);

    // ---------------- NLM swap at h2 ----------------
    nlm_prep_kernel<<<cdiv(5308416, 256), 256, 0, stream>>>(h2, xT, N, 512, 1296);
    nlm_sq_kernel<<<cdiv(N * 1296, 256), 256, 0, stream>>>(xT, sqb, N * 1296, 512);
    hipMemcpyAsync(h2s, h2, (size_t)5308416 * sizeof(float), hipMemcpyDeviceToDevice, stream);
    nlm_kernel<<<dim3(1296, N), 256, 0, stream>>>(xT, sqb, nm2, h2s, 1.f / 25.f);

    // ---------------- enc3: 512->512, 3x3 s2 p1, BN+relu ----------------
    maskconv_kernel<3, 2, false><<<cdiv(N * 18 * 18, 256), 256, 0, stream>>>(
        nm2, 36, 36, mc, nm3, N, 36, 36, 18, 18);
    {
        int HWT = 18 * 5;
        pconv_kernel<3, 2, false, false><<<dim3(cdiv(HWT, 64), 512, N), 64, 0, stream>>>(
            h2s, 512, 36, 36, nullptr, 0, nm2, 36, 36, enc3W, mc, nullptr,
            h3, 36, 36, 18, 18, 512, ACT_NONE);
    }
    bn_stats_kernel<<<512, 256, 0, stream>>>(h3, N, 512, 324, bmean, bistd);
    bn_apply_kernel<<<cdiv(1327104, 256), 256, 0, stream>>>(h3, bmean, bistd, enc3g, enc3b,
                                                            512, 324, 1327104, ACT_RELU);

    // ---------------- enc4: 512->512, 3x3 s2 p1, BN+relu ----------------
    maskconv_kernel<3, 2, false><<<cdiv(N * 9 * 9, 256), 256, 0, stream>>>(
        nm3, 18, 18, mc, nm4, N, 18, 18, 9, 9);
    {
        int HWT = 9 * 3;
        pconv_kernel<3, 2, false, false><<<dim3(cdiv(HWT, 64), 512, N), 64, 0, stream>>>(
            h3, 512, 18, 18, nullptr, 0, nm3, 18, 18, enc4W, mc, nullptr,
            h4, 18, 18, 9, 9, 512, ACT_NONE);
    }
    bn_stats_kernel<<<512, 256, 0, stream>>>(h4, N, 512, 81, bmean, bistd);
    bn_apply_kernel<<<cdiv(331776, 256), 256, 0, stream>>>(h4, bmean, bistd, enc4g, enc4b,
                                                           512, 81, 331776, ACT_RELU);

    // ---------------- dec4: cat[up2(h4), h3] 1024->512 @18, BN+leaky ----------------
    maskconv_kernel<3, 1, true><<<cdiv(N * 18 * 18, 256), 256, 0, stream>>>(
        nm4, 9, 9, mc, nmd4, N, 18, 18, 18, 18);
    {
        int HWT = 18 * 5;
        pconv_kernel<3, 1, true, true><<<dim3(cdiv(HWT, 64), 512, N), 64, 0, stream>>>(
            h4, 512, 9, 9, h3, 512, nm4, 9, 9, dec4W, mc, nullptr,
            d4, 18, 18, 18, 18, 512, ACT_NONE);
    }
    bn_stats_kernel<<<512, 256, 0, stream>>>(d4, N, 512, 324, bmean, bistd);
    bn_apply_kernel<<<cdiv(1327104, 256), 256, 0, stream>>>(d4, bmean, bistd, dec4g, dec4b,
                                                            512, 324, 1327104, ACT_LEAKY);

    // ---------------- dec3: cat[up2(d4), h2s] 1024->512 @36, BN+leaky ----------------
    maskconv_kernel<3, 1, true><<<cdiv(N * 36 * 36, 256), 256, 0, stream>>>(
        nmd4, 18, 18, mc, nmd3, N, 36, 36, 36, 36);
    {
        int HWT = 36 * 9;
        pconv_kernel<3, 1, true, true><<<dim3(cdiv(HWT, 256), 512, N), 256, 0, stream>>>(
            d4, 512, 18, 18, h2s, 512, nmd4, 18, 18, dec3W, mc, nullptr,
            d3, 36, 36, 36, 36, 512, ACT_NONE);
    }
    bn_stats_kernel<<<512, 256, 0, stream>>>(d3, N, 512, 1296, bmean, bistd);
    bn_apply_kernel<<<cdiv(5308416, 256), 256, 0, stream>>>(d3, bmean, bistd, dec3g, dec3b,
                                                            512, 1296, 5308416, ACT_LEAKY);

    // ---------------- dec2: cat[up2(d3), h1] 768->256 @72, BN+leaky ----------------
    maskconv_kernel<3, 1, true><<<cdiv(N * 72 * 72, 256), 256, 0, stream>>>(
        nmd3, 36, 36, mc, nmd2, N, 72, 72, 72, 72);
    {
        int HWT = 72 * 18;
        pconv_kernel<3, 1, true, true><<<dim3(cdiv(HWT, 256), 256, N), 256, 0, stream>>>(
            d3, 512, 36, 36, h1, 256, nmd3, 36, 36, dec2W, mc, nullptr,
            d2, 72, 72, 72, 72, 256, ACT_NONE);
    }
    bn_stats_kernel<<<256, 256, 0, stream>>>(d2, N, 256, 5184, bmean, bistd);
    bn_apply_kernel<<<cdiv(10616832, 256), 256, 0, stream>>>(d2, bmean, bistd, dec2g, dec2b,
                                                             256, 5184, 10616832, ACT_LEAKY);

    // ---------------- dec1: cat[up2(d2), x0] 384->128 @144, bias, no BN/act ----------------
    maskconv_kernel<3, 1, true><<<cdiv(N * 144 * 144, 256), 256, 0, stream>>>(
        nmd2, 72, 72, mc, nmx, N, 144, 144, 144, 144);
    {
        int HWT = 144 * 36;
        pconv_kernel<3, 1, true, true><<<dim3(cdiv(HWT, 256), 128, N), 256, 0, stream>>>(
            d2, 256, 72, 72, x0, 128, nmd2, 72, 72, dec1W, mc, dec1b,
            outp, 144, 144, 144, 144, 128, ACT_NONE);
    }
}

// Round 2
// 5404.615 us; speedup vs baseline: 56.7543x; 56.7543x over previous
//
#include <hip/hip_runtime.h>
#include <math.h>

#define ACT_NONE 0
#define ACT_RELU 1
#define ACT_LEAKY 2

#define EPI_F32 0
#define EPI_PAIR_RELU 1
#define EPI_F32_BIAS 2

typedef __attribute__((ext_vector_type(8))) short short8;
typedef __attribute__((ext_vector_type(8))) __bf16 bf16x8;
typedef __attribute__((ext_vector_type(4))) float f32x4;

__device__ __forceinline__ float actf(float y, int act) {
    if (act == ACT_RELU)  return y > 0.f ? y : 0.f;
    if (act == ACT_LEAKY) return y >= 0.f ? y : 0.2f * y;
    return y;
}

// ---- bf16 split helpers: f32 -> (hi,lo) bf16 pair packed in u32 (hi in low 16) ----
__device__ __forceinline__ unsigned f2bf_rne(float f) {
    unsigned u = __float_as_uint(f);
    return (u + 0x7FFFu + ((u >> 16) & 1u)) >> 16;
}
__device__ __forceinline__ float bf2f(unsigned h) { return __uint_as_float(h << 16); }
__device__ __forceinline__ unsigned splitpack(float f) {
    unsigned hi = f2bf_rne(f);
    float r = f - bf2f(hi);
    unsigned lo = f2bf_rne(r);
    return (hi & 0xFFFFu) | (lo << 16);
}

__device__ __forceinline__ f32x4 mfma16(short8 a, short8 b, f32x4 c) {
    return __builtin_amdgcn_mfma_f32_16x16x32_bf16(
        __builtin_bit_cast(bf16x8, a), __builtin_bit_cast(bf16x8, b), c, 0, 0, 0);
}

// ---------------------------------------------------------------------------
// Mask convolution: mc = conv(mask, ones(K,K), stride S, pad P); nm = (mc!=0)
// ---------------------------------------------------------------------------
template<int K, int S, bool MHALF>
__global__ void maskconv_kernel(const float* __restrict__ M, int HM, int WM,
                                float* __restrict__ mc, float* __restrict__ nm,
                                int N, int Hin, int Win, int Hout, int Wout) {
    constexpr int P = (K - 1) / 2;
    int idx = blockIdx.x * blockDim.x + threadIdx.x;
    int total = N * Hout * Wout;
    if (idx >= total) return;
    int wo = idx % Wout;
    int t  = idx / Wout;
    int ho = t % Hout;
    int n  = t / Hout;
    float s = 0.f;
    for (int kh = 0; kh < K; ++kh) {
        int ih = ho * S - P + kh;
        if ((unsigned)ih >= (unsigned)Hin) continue;
        const float* mrow = M + ((size_t)n * HM + (MHALF ? (ih >> 1) : ih)) * WM;
        for (int kw = 0; kw < K; ++kw) {
            int iw = wo * S - P + kw;
            if ((unsigned)iw < (unsigned)Win)
                s += mrow[MHALF ? (iw >> 1) : iw];
        }
    }
    mc[idx] = s;
    nm[idx] = (s == 0.f) ? 0.f : 1.f;
}

// ---------------------------------------------------------------------------
// Weight transform: W[co][ci][kh][kw] f32 -> A-fragment layout bf16 hi/lo
// layout: elem idx = (((tap*KB + kb)*COB + cob)*64 + lane)*8 + j
//   co = cob*16 + (lane&15); ci = kb*32 + (lane>>4)*8 + j; tap = kh*K+kw
// ---------------------------------------------------------------------------
__global__ void wtransform(const float* __restrict__ W, short* __restrict__ Whi,
                           short* __restrict__ Wlo, int Cout, int Cin, int Ksz,
                           size_t total) {
    size_t idx = (size_t)blockIdx.x * blockDim.x + threadIdx.x;
    if (idx >= total) return;
    int j = (int)(idx & 7);
    int lane = (int)((idx >> 3) & 63);
    size_t r = idx >> 9;
    int COB = Cout >> 4, KB = Cin >> 5;
    int cob = (int)(r % COB); r /= COB;
    int kb = (int)(r % KB);
    int tap = (int)(r / KB);
    int co = cob * 16 + (lane & 15);
    int ci = kb * 32 + (lane >> 4) * 8 + j;
    float f = W[((size_t)co * Cin + ci) * Ksz + tap];
    unsigned hi = f2bf_rne(f);
    float rr = f - bf2f(hi);
    unsigned lo = f2bf_rne(rr);
    Whi[idx] = (short)hi;
    Wlo[idx] = (short)lo;
}

// ---------------------------------------------------------------------------
// MFMA implicit-GEMM partial conv.
//   M(GEMM)=Cout (BM=128), N(GEMM)=out pixels (BN=64), K(GEMM)=Cin (BK=32) x K*K taps
//   A = weights in fragment layout (global, bf16 hi/lo), B = masked input staged
//   to LDS as bf16 hi/lo (inputs pre-split into packed u32 pairs, or f32 inline).
//   512 threads = 8 waves (4m x 2n), each wave 32x32 via 2x2 16x16 frags.
//   3-product bf16x2: hi*hi + hi*lo + lo*hi.
// ---------------------------------------------------------------------------
template<int K, int S, bool UPA, bool MHALF, bool AF32, bool BF32, int EPI>
__global__ __launch_bounds__(512) void conv_mfma(
    const void* __restrict__ Asrc, int CA, int HA, int WA,
    const void* __restrict__ Bsrc, int CB,
    const float* __restrict__ M, int HM, int WM,
    const short* __restrict__ Whi, const short* __restrict__ Wlo,
    const float* __restrict__ mc, const float* __restrict__ bias,
    void* __restrict__ outp,
    int Hin, int Win, int Hout, int Wout, int Cout)
{
    constexpr int P = (K - 1) / 2;
    __shared__ __align__(16) unsigned BHs[1024];   // [kgrp4][n64][4 dwords]
    __shared__ __align__(16) unsigned BLs[1024];

    const int t    = threadIdx.x;
    const int lane = t & 63;
    const int wv   = t >> 6;
    const int wm   = wv >> 1;    // 0..3 : m-quadrant (32 rows)
    const int wn   = wv & 1;     // 0..1 : n-half (32 cols)
    const int img  = blockIdx.z;
    const int coB  = blockIdx.y * 128;
    const int Npix = Hout * Wout;
    const int p0   = blockIdx.x * 64;
    const int Cin  = CA + CB;
    const int KB   = Cin >> 5;
    const int COB  = Cout >> 4;

    // staging coords: thread handles pixel sn, k-subrange sk*4..sk*4+3
    const int sn = t & 63;
    const int sk = t >> 6;
    const unsigned wofs = ((unsigned)((sk >> 1) * 64 + sn) * 4u) + (unsigned)(sk & 1) * 2u;

    const int sp = p0 + sn;
    const bool pval = sp < Npix;
    const int ho = pval ? sp / Wout : 0;
    const int wo = pval ? sp - ho * Wout : 0;

    f32x4 acc[2][2] = {};
    const size_t HWA = (size_t)HA * WA;
    const size_t HWB = (size_t)Hin * Win;

#pragma unroll 1
    for (int kh = 0; kh < K; ++kh)
#pragma unroll 1
    for (int kw = 0; kw < K; ++kw) {
        const int tap = kh * K + kw;
        const int ih = ho * S - P + kh;
        const int iw = wo * S - P + kw;
        const bool inb = pval && (unsigned)ih < (unsigned)Hin && (unsigned)iw < (unsigned)Win;
        bool sel = false;
        if (inb)
            sel = M[(size_t)img * HM * WM + (size_t)(MHALF ? (ih >> 1) : ih) * WM
                    + (MHALF ? (iw >> 1) : iw)] != 0.f;
        const size_t aofs = (size_t)img * CA * HWA
                          + (size_t)(UPA ? (ih >> 1) : ih) * WA + (UPA ? (iw >> 1) : iw);
        const size_t bofs = (size_t)img * CB * HWB + (size_t)ih * Win + iw;
        const size_t wtap = (size_t)tap * KB;

#pragma unroll 1
        for (int kb = 0; kb < KB; ++kb) {
            const int ci0 = kb * 32 + sk * 4;
            unsigned v0 = 0, v1 = 0, v2 = 0, v3 = 0;
            if (sel) {
                if (ci0 < CA) {
                    if (AF32) {
                        const float* s = (const float*)Asrc + aofs + (size_t)ci0 * HWA;
                        v0 = splitpack(s[0]); v1 = splitpack(s[HWA]);
                        v2 = splitpack(s[2 * HWA]); v3 = splitpack(s[3 * HWA]);
                    } else {
                        const unsigned* s = (const unsigned*)Asrc + aofs + (size_t)ci0 * HWA;
                        v0 = s[0]; v1 = s[HWA]; v2 = s[2 * HWA]; v3 = s[3 * HWA];
                    }
                } else {
                    const int cb0 = ci0 - CA;
                    if (BF32) {
                        const float* s = (const float*)Bsrc + bofs + (size_t)cb0 * HWB;
                        v0 = splitpack(s[0]); v1 = splitpack(s[HWB]);
                        v2 = splitpack(s[2 * HWB]); v3 = splitpack(s[3 * HWB]);
                    } else {
                        const unsigned* s = (const unsigned*)Bsrc + bofs + (size_t)cb0 * HWB;
                        v0 = s[0]; v1 = s[HWB]; v2 = s[2 * HWB]; v3 = s[3 * HWB];
                    }
                }
            }
            BHs[wofs]     = (v0 & 0xFFFFu) | (v1 << 16);
            BHs[wofs + 1] = (v2 & 0xFFFFu) | (v3 << 16);
            BLs[wofs]     = (v0 >> 16) | (v1 & 0xFFFF0000u);
            BLs[wofs + 1] = (v2 >> 16) | (v3 & 0xFFFF0000u);
            __syncthreads();

            // A fragments: direct coalesced global b128 loads (L2-resident)
            const short* wp = Whi + ((wtap + kb) * COB + (coB >> 4) + wm * 2) * 512 + lane * 8;
            const short* lp = Wlo + ((wtap + kb) * COB + (coB >> 4) + wm * 2) * 512 + lane * 8;
            short8 ah0 = *(const short8*)wp;
            short8 ah1 = *(const short8*)(wp + 512);
            short8 al0 = *(const short8*)lp;
            short8 al1 = *(const short8*)(lp + 512);

            // B fragments from LDS
            const int rb = ((lane >> 4) * 64 + (lane & 15)) * 4;
            short8 bh0 = *(const short8*)&BHs[rb + (wn * 2 + 0) * 64];
            short8 bh1 = *(const short8*)&BHs[rb + (wn * 2 + 1) * 64];
            short8 bl0 = *(const short8*)&BLs[rb + (wn * 2 + 0) * 64];
            short8 bl1 = *(const short8*)&BLs[rb + (wn * 2 + 1) * 64];

            acc[0][0] = mfma16(ah0, bh0, acc[0][0]);
            acc[0][1] = mfma16(ah0, bh1, acc[0][1]);
            acc[1][0] = mfma16(ah1, bh0, acc[1][0]);
            acc[1][1] = mfma16(ah1, bh1, acc[1][1]);
            acc[0][0] = mfma16(ah0, bl0, acc[0][0]);
            acc[0][1] = mfma16(ah0, bl1, acc[0][1]);
            acc[1][0] = mfma16(ah1, bl0, acc[1][0]);
            acc[1][1] = mfma16(ah1, bl1, acc[1][1]);
            acc[0][0] = mfma16(al0, bh0, acc[0][0]);
            acc[0][1] = mfma16(al0, bh1, acc[0][1]);
            acc[1][0] = mfma16(al1, bh0, acc[1][0]);
            acc[1][1] = mfma16(al1, bh1, acc[1][1]);
            __syncthreads();
        }
    }

    // epilogue: renorm by mc, optional bias trick / relu, store
    const float* mcb = mc + (size_t)img * Npix;
#pragma unroll
    for (int fm = 0; fm < 2; ++fm)
#pragma unroll
    for (int fn = 0; fn < 2; ++fn) {
        const int co = coB + wm * 32 + fm * 16 + (lane >> 4) * 4;
        const int px = p0 + wn * 32 + fn * 16 + (lane & 15);
        if (px >= Npix) continue;
        const float m = mcb[px];
        f32x4 a = acc[fm][fn];
#pragma unroll
        for (int r = 0; r < 4; ++r) {
            float y = a[r];
            if (EPI == EPI_F32_BIAS) {
                const float bv = bias[co + r];
                y = (m == 0.f) ? 0.f : (y - bv) / m + bv;
            } else {
                y = (m == 0.f) ? 0.f : y / m;
            }
            const size_t oidx = ((size_t)img * Cout + co + r) * Npix + px;
            if (EPI == EPI_PAIR_RELU) {
                y = y > 0.f ? y : 0.f;
                ((unsigned*)outp)[oidx] = splitpack(y);
            } else {
                ((float*)outp)[oidx] = y;
            }
        }
    }
}

// ---------------------------------------------------------------------------
// BatchNorm (training-mode, biased var over N,H,W)
// ---------------------------------------------------------------------------
__global__ __launch_bounds__(256) void bn_stats_kernel(const float* __restrict__ y,
                                                       int N, int C, int HW,
                                                       float* __restrict__ mean,
                                                       float* __restrict__ istd) {
    const int c = blockIdx.x;
    double s = 0.0, s2 = 0.0;
    const int tot = N * HW;
    for (int i = threadIdx.x; i < tot; i += blockDim.x) {
        int n = i / HW, hw = i - n * HW;
        float v = y[((size_t)n * C + c) * HW + hw];
        s += v;
        s2 += (double)v * v;
    }
    __shared__ double sh[256], sh2[256];
    sh[threadIdx.x] = s; sh2[threadIdx.x] = s2;
    __syncthreads();
    for (int o = 128; o > 0; o >>= 1) {
        if (threadIdx.x < o) { sh[threadIdx.x] += sh[threadIdx.x + o]; sh2[threadIdx.x] += sh2[threadIdx.x + o]; }
        __syncthreads();
    }
    if (threadIdx.x == 0) {
        double mu = sh[0] / tot;
        double var = sh2[0] / tot - mu * mu;
        mean[c] = (float)mu;
        istd[c] = (float)(1.0 / sqrt(var + 1e-5));
    }
}

// BN apply + act; writes packed bf16-pair (and optional f32 copy)
__global__ void bn_apply_pair(const float* __restrict__ y,
                              const float* __restrict__ mean, const float* __restrict__ istd,
                              const float* __restrict__ g, const float* __restrict__ b,
                              unsigned* __restrict__ pout, float* __restrict__ fout,
                              int C, int HW, int total, int act) {
    int idx = blockIdx.x * blockDim.x + threadIdx.x;
    if (idx >= total) return;
    int c = (idx / HW) % C;
    float v = (y[idx] - mean[c]) * istd[c] * g[c] + b[c];
    v = actf(v, act);
    pout[idx] = splitpack(v);
    if (fout) fout[idx] = v;
}

// ---------------------------------------------------------------------------
// NLM feature swapping at h2 (B=8, C=512, Npix=1296)
// ---------------------------------------------------------------------------
#define NLM_C 512
#define NLM_N 1296

__global__ void nlm_prep_kernel(const float* __restrict__ h2, float* __restrict__ xT,
                                int Bn, int C, int Npix) {
    size_t idx = (size_t)blockIdx.x * blockDim.x + threadIdx.x;
    size_t total = (size_t)Bn * Npix * C;
    if (idx >= total) return;
    int c = (int)(idx % C);
    size_t t = idx / C;
    int j = (int)(t % Npix);
    int b = (int)(t / Npix);
    xT[idx] = h2[((size_t)b * C + c) * Npix + j];
}

__global__ void nlm_sq_kernel(const float* __restrict__ xT, float* __restrict__ sq,
                              int BN, int C) {
    int idx = blockIdx.x * blockDim.x + threadIdx.x;
    if (idx >= BN) return;
    const float* r = xT + (size_t)idx * C;
    float s = 0.f;
    for (int c = 0; c < C; ++c) s = fmaf(r[c], r[c], s);
    sq[idx] = s;
}

__global__ __launch_bounds__(256) void nlm_kernel(
    const float* __restrict__ xT, const float* __restrict__ sq,
    const float* __restrict__ mask,
    unsigned* __restrict__ out,     // packed bf16-pair h2s, NCHW
    float inv_h2) {
    const int i = blockIdx.x;
    const int b = blockIdx.y;
    const int tid = threadIdx.x;
    if (mask[(size_t)b * NLM_N + i] > 0.5f) return;  // background: keep pair written by bn_apply

    __shared__ float Drow[NLM_N];
    __shared__ float xi[NLM_C];
    __shared__ float red[256];

    const float* xib = xT + ((size_t)b * NLM_N + i) * NLM_C;
    for (int c = tid; c < NLM_C; c += 256) xi[c] = xib[c];
    __syncthreads();

    const float sqi = sq[(size_t)b * NLM_N + i];
    const float BIG = 3.4e38f;
    float lmin = BIG;
    for (int j = tid; j < NLM_N; j += 256) {
        float d = BIG;
        if (mask[(size_t)b * NLM_N + j] > 0.5f) {
            const float* xj = xT + ((size_t)b * NLM_N + j) * NLM_C;
            float dot = 0.f;
            for (int c = 0; c < NLM_C; ++c) dot = fmaf(xi[c], xj[c], dot);
            d = sqi + sq[(size_t)b * NLM_N + j] - 2.f * dot;
            d = d > 0.f ? d : 0.f;
            lmin = d < lmin ? d : lmin;
        }
        Drow[j] = d;
    }
    red[tid] = lmin;
    __syncthreads();
    for (int o = 128; o > 0; o >>= 1) {
        if (tid < o) red[tid] = fminf(red[tid], red[tid + o]);
        __syncthreads();
    }
    const float dmin = red[0];
    __syncthreads();

    float lsum = 0.f;
    for (int j = tid; j < NLM_N; j += 256) {
        float wv = 0.f;
        if (Drow[j] < 3.3e38f) wv = expf(-(Drow[j] - dmin) * inv_h2);
        Drow[j] = wv;
        lsum += wv;
    }
    red[tid] = lsum;
    __syncthreads();
    for (int o = 128; o > 0; o >>= 1) {
        if (tid < o) red[tid] += red[tid + o];
        __syncthreads();
    }
    const float invw = 1.f / red[0];
    __syncthreads();

    for (int c = tid; c < NLM_C; c += 256) {
        float a = 0.f;
        for (int j = 0; j < NLM_N; ++j)
            a = fmaf(Drow[j], xT[((size_t)b * NLM_N + j) * NLM_C + c], a);
        out[((size_t)b * NLM_C + c) * NLM_N + i] = splitpack(a * invw);
    }
}

// ---------------------------------------------------------------------------
// Driver
// ---------------------------------------------------------------------------
extern "C" void kernel_launch(void* const* d_in, const int* in_sizes, int n_in,
                              void* d_out, int out_size, void* d_ws, size_t ws_size,
                              hipStream_t stream) {
    const float* x0    = (const float*)d_in[0];
    const float* m0    = (const float*)d_in[1];
    const float* Wsrc[8] = {
        (const float*)d_in[2], (const float*)d_in[3], (const float*)d_in[4],
        (const float*)d_in[5], (const float*)d_in[6], (const float*)d_in[7],
        (const float*)d_in[8], (const float*)d_in[9]
    };
    const float* dec1b = (const float*)d_in[10];
    const float* enc2g = (const float*)d_in[11];
    const float* enc2b = (const float*)d_in[12];
    const float* enc3g = (const float*)d_in[13];
    const float* enc3b = (const float*)d_in[14];
    const float* enc4g = (const float*)d_in[15];
    const float* enc4b = (const float*)d_in[16];
    const float* dec4g = (const float*)d_in[17];
    const float* dec4b = (const float*)d_in[18];
    const float* dec3g = (const float*)d_in[19];
    const float* dec3b = (const float*)d_in[20];
    const float* dec2g = (const float*)d_in[21];
    const float* dec2b = (const float*)d_in[22];
    float* outp = (float*)d_out;

    const int N = 8;
    float* ws = (float*)d_ws;
    size_t off = 0;
    auto alloc = [&](size_t nf) {
        size_t o = off;
        off += ((nf + 63) / 64) * 64;
        return ws + o;
    };

    unsigned* h1pair  = (unsigned*)alloc(10616832);  // 8x256x72x72  (later d2pair)
    unsigned* h2spair = (unsigned*)alloc(5308416);   // 8x512x36x36  (later d3pair)
    unsigned* h3pair  = (unsigned*)alloc(1327104);   // 8x512x18x18
    unsigned* h4pair  = (unsigned*)alloc(331776);    // 8x512x9x9
    unsigned* d4pair  = (unsigned*)alloc(1327104);
    float* ybuf = alloc(10616832);                   // pre-BN f32 scratch (max dec2)
    float* h2f  = alloc(5308416);                    // f32 h2 for NLM
    float* xT   = alloc(5308416);
    float* sqb  = alloc(10368);
    float* mc   = alloc(165888);
    float* nm1  = alloc(41472);
    float* nm2  = alloc(10368);
    float* nm3  = alloc(2592);
    float* nm4  = alloc(648);
    float* nmd4 = alloc(2592);
    float* nmd3 = alloc(10368);
    float* nmd2 = alloc(41472);
    float* nmx  = alloc(165888);
    float* bmean = alloc(512);
    float* bistd = alloc(512);
    short* Whi = (short*)alloc(10625024);            // 21,250,048 bf16
    short* Wlo = (short*)alloc(10625024);
    unsigned* d3pair = h2spair;  // h2spair dead after dec3 conv
    unsigned* d2pair = h1pair;   // h1pair dead after dec2 conv

    if (ws_size < off * sizeof(float)) return;  // workspace too small; fail loudly

    auto cdiv = [](size_t a, size_t b) { return (int)((a + b - 1) / b); };

    // ---- weight transforms (A-fragment layout, bf16 hi/lo) ----
    struct WLay { int Cout, Cin, K; size_t ofs; };
    const WLay WL[8] = {
        {256, 128, 7, 0},         // enc1
        {512, 256, 5, 1605632},   // enc2
        {512, 512, 3, 4882432},   // enc3
        {512, 512, 3, 7241728},   // enc4
        {512, 1024, 3, 9601024},  // dec4
        {512, 1024, 3, 14319616}, // dec3
        {256, 768, 3, 19038208},  // dec2
        {128, 384, 3, 20807680},  // dec1
    };
    for (int i = 0; i < 8; ++i) {
        size_t tot = (size_t)WL[i].Cout * WL[i].Cin * WL[i].K * WL[i].K;
        wtransform<<<cdiv(tot, 256), 256, 0, stream>>>(
            Wsrc[i], Whi + WL[i].ofs, Wlo + WL[i].ofs, WL[i].Cout, WL[i].Cin,
            WL[i].K * WL[i].K, tot);
    }

    // ---------------- enc1: 128->256, 7x7 s2 p3, relu, no BN ----------------
    maskconv_kernel<7, 2, false><<<cdiv(N * 72 * 72, 256), 256, 0, stream>>>(
        m0, 144, 144, mc, nm1, N, 144, 144, 72, 72);
    conv_mfma<7, 2, false, false, true, false, EPI_PAIR_RELU>
        <<<dim3(81, 2, N), 512, 0, stream>>>(
        x0, 128, 144, 144, nullptr, 0, m0, 144, 144,
        Whi + WL[0].ofs, Wlo + WL[0].ofs, mc, nullptr, h1pair,
        144, 144, 72, 72, 256);

    // ---------------- enc2: 256->512, 5x5 s2 p2, BN+relu ----------------
    maskconv_kernel<5, 2, false><<<cdiv(N * 36 * 36, 256), 256, 0, stream>>>(
        nm1, 72, 72, mc, nm2, N, 72, 72, 36, 36);
    conv_mfma<5, 2, false, false, false, false, EPI_F32>
        <<<dim3(21, 4, N), 512, 0, stream>>>(
        h1pair, 256, 72, 72, nullptr, 0, nm1, 72, 72,
        Whi + WL[1].ofs, Wlo + WL[1].ofs, mc, nullptr, ybuf,
        72, 72, 36, 36, 512);
    bn_stats_kernel<<<512, 256, 0, stream>>>(ybuf, N, 512, 1296, bmean, bistd);
    bn_apply_pair<<<cdiv(5308416, 256), 256, 0, stream>>>(
        ybuf, bmean, bistd, enc2g, enc2b, h2spair, h2f, 512, 1296, 5308416, ACT_RELU);

    // ---------------- NLM swap at h2 ----------------
    nlm_prep_kernel<<<cdiv(5308416, 256), 256, 0, stream>>>(h2f, xT, N, 512, 1296);
    nlm_sq_kernel<<<cdiv(N * 1296, 256), 256, 0, stream>>>(xT, sqb, N * 1296, 512);
    nlm_kernel<<<dim3(1296, N), 256, 0, stream>>>(xT, sqb, nm2, h2spair, 1.f / 25.f);

    // ---------------- enc3: 512->512, 3x3 s2 p1, BN+relu ----------------
    maskconv_kernel<3, 2, false><<<cdiv(N * 18 * 18, 256), 256, 0, stream>>>(
        nm2, 36, 36, mc, nm3, N, 36, 36, 18, 18);
    conv_mfma<3, 2, false, false, false, false, EPI_F32>
        <<<dim3(6, 4, N), 512, 0, stream>>>(
        h2spair, 512, 36, 36, nullptr, 0, nm2, 36, 36,
        Whi + WL[2].ofs, Wlo + WL[2].ofs, mc, nullptr, ybuf,
        36, 36, 18, 18, 512);
    bn_stats_kernel<<<512, 256, 0, stream>>>(ybuf, N, 512, 324, bmean, bistd);
    bn_apply_pair<<<cdiv(1327104, 256), 256, 0, stream>>>(
        ybuf, bmean, bistd, enc3g, enc3b, h3pair, nullptr, 512, 324, 1327104, ACT_RELU);

    // ---------------- enc4: 512->512, 3x3 s2 p1, BN+relu ----------------
    maskconv_kernel<3, 2, false><<<cdiv(N * 9 * 9, 256), 256, 0, stream>>>(
        nm3, 18, 18, mc, nm4, N, 18, 18, 9, 9);
    conv_mfma<3, 2, false, false, false, false, EPI_F32>
        <<<dim3(2, 4, N), 512, 0, stream>>>(
        h3pair, 512, 18, 18, nullptr, 0, nm3, 18, 18,
        Whi + WL[3].ofs, Wlo + WL[3].ofs, mc, nullptr, ybuf,
        18, 18, 9, 9, 512);
    bn_stats_kernel<<<512, 256, 0, stream>>>(ybuf, N, 512, 81, bmean, bistd);
    bn_apply_pair<<<cdiv(331776, 256), 256, 0, stream>>>(
        ybuf, bmean, bistd, enc4g, enc4b, h4pair, nullptr, 512, 81, 331776, ACT_RELU);

    // ---------------- dec4: cat[up2(h4), h3] 1024->512 @18, BN+leaky ----------------
    maskconv_kernel<3, 1, true><<<cdiv(N * 18 * 18, 256), 256, 0, stream>>>(
        nm4, 9, 9, mc, nmd4, N, 18, 18, 18, 18);
    conv_mfma<3, 1, true, true, false, false, EPI_F32>
        <<<dim3(6, 4, N), 512, 0, stream>>>(
        h4pair, 512, 9, 9, h3pair, 512, nm4, 9, 9,
        Whi + WL[4].ofs, Wlo + WL[4].ofs, mc, nullptr, ybuf,
        18, 18, 18, 18, 512);
    bn_stats_kernel<<<512, 256, 0, stream>>>(ybuf, N, 512, 324, bmean, bistd);
    bn_apply_pair<<<cdiv(1327104, 256), 256, 0, stream>>>(
        ybuf, bmean, bistd, dec4g, dec4b, d4pair, nullptr, 512, 324, 1327104, ACT_LEAKY);

    // ---------------- dec3: cat[up2(d4), h2s] 1024->512 @36, BN+leaky ----------------
    maskconv_kernel<3, 1, true><<<cdiv(N * 36 * 36, 256), 256, 0, stream>>>(
        nmd4, 18, 18, mc, nmd3, N, 36, 36, 36, 36);
    conv_mfma<3, 1, true, true, false, false, EPI_F32>
        <<<dim3(21, 4, N), 512, 0, stream>>>(
        d4pair, 512, 18, 18, h2spair, 512, nmd4, 18, 18,
        Whi + WL[5].ofs, Wlo + WL[5].ofs, mc, nullptr, ybuf,
        36, 36, 36, 36, 512);
    bn_stats_kernel<<<512, 256, 0, stream>>>(ybuf, N, 512, 1296, bmean, bistd);
    bn_apply_pair<<<cdiv(5308416, 256), 256, 0, stream>>>(
        ybuf, bmean, bistd, dec3g, dec3b, d3pair, nullptr, 512, 1296, 5308416, ACT_LEAKY);

    // ---------------- dec2: cat[up2(d3), h1] 768->256 @72, BN+leaky ----------------
    maskconv_kernel<3, 1, true><<<cdiv(N * 72 * 72, 256), 256, 0, stream>>>(
        nmd3, 36, 36, mc, nmd2, N, 72, 72, 72, 72);
    conv_mfma<3, 1, true, true, false, false, EPI_F32>
        <<<dim3(81, 2, N), 512, 0, stream>>>(
        d3pair, 512, 36, 36, h1pair, 256, nmd3, 36, 36,
        Whi + WL[6].ofs, Wlo + WL[6].ofs, mc, nullptr, ybuf,
        72, 72, 72, 72, 256);
    bn_stats_kernel<<<256, 256, 0, stream>>>(ybuf, N, 256, 5184, bmean, bistd);
    bn_apply_pair<<<cdiv(10616832, 256), 256, 0, stream>>>(
        ybuf, bmean, bistd, dec2g, dec2b, d2pair, nullptr, 256, 5184, 10616832, ACT_LEAKY);

    // ---------------- dec1: cat[up2(d2), x0] 384->128 @144, bias, no BN/act ----------------
    maskconv_kernel<3, 1, true><<<cdiv(N * 144 * 144, 256), 256, 0, stream>>>(
        nmd2, 72, 72, mc, nmx, N, 144, 144, 144, 144);
    conv_mfma<3, 1, true, true, false, true, EPI_F32_BIAS>
        <<<dim3(324, 1, N), 512, 0, stream>>>(
        d2pair, 256, 72, 72, x0, 128, nmd2, 72, 72,
        Whi + WL[7].ofs, Wlo + WL[7].ofs, mc, dec1b, outp,
        144, 144, 144, 144, 128);
}

// Round 3
// 4864.329 us; speedup vs baseline: 63.0581x; 1.1111x over previous
//
#include <hip/hip_runtime.h>
#include <math.h>

#define ACT_NONE 0
#define ACT_RELU 1
#define ACT_LEAKY 2

#define EPI_F32 0
#define EPI_PAIR_RELU 1
#define EPI_F32_BIAS 2

typedef __attribute__((ext_vector_type(8))) short short8;
typedef __attribute__((ext_vector_type(8))) __bf16 bf16x8;
typedef __attribute__((ext_vector_type(4))) float f32x4;
typedef __attribute__((ext_vector_type(4))) unsigned uint4v;

__device__ __forceinline__ float actf(float y, int act) {
    if (act == ACT_RELU)  return y > 0.f ? y : 0.f;
    if (act == ACT_LEAKY) return y >= 0.f ? y : 0.2f * y;
    return y;
}

// ---- bf16 split helpers: f32 -> (hi,lo) bf16 pair packed in u32 (hi in low 16) ----
__device__ __forceinline__ unsigned f2bf_rne(float f) {
    unsigned u = __float_as_uint(f);
    return (u + 0x7FFFu + ((u >> 16) & 1u)) >> 16;
}
__device__ __forceinline__ float bf2f(unsigned h) { return __uint_as_float(h << 16); }
__device__ __forceinline__ unsigned splitpack(float f) {
    unsigned hi = f2bf_rne(f);
    float r = f - bf2f(hi);
    unsigned lo = f2bf_rne(r);
    return (hi & 0xFFFFu) | (lo << 16);
}

__device__ __forceinline__ f32x4 mfma16(short8 a, short8 b, f32x4 c) {
    return __builtin_amdgcn_mfma_f32_16x16x32_bf16(
        __builtin_bit_cast(bf16x8, a), __builtin_bit_cast(bf16x8, b), c, 0, 0, 0);
}

// ---------------------------------------------------------------------------
// Mask convolution: mc = conv(mask, ones(K,K), stride S, pad P); nm = (mc!=0)
// ---------------------------------------------------------------------------
template<int K, int S, bool MHALF>
__global__ void maskconv_kernel(const float* __restrict__ M, int HM, int WM,
                                float* __restrict__ mc, float* __restrict__ nm,
                                int N, int Hin, int Win, int Hout, int Wout) {
    constexpr int P = (K - 1) / 2;
    int idx = blockIdx.x * blockDim.x + threadIdx.x;
    int total = N * Hout * Wout;
    if (idx >= total) return;
    int wo = idx % Wout;
    int t  = idx / Wout;
    int ho = t % Hout;
    int n  = t / Hout;
    float s = 0.f;
    for (int kh = 0; kh < K; ++kh) {
        int ih = ho * S - P + kh;
        if ((unsigned)ih >= (unsigned)Hin) continue;
        const float* mrow = M + ((size_t)n * HM + (MHALF ? (ih >> 1) : ih)) * WM;
        for (int kw = 0; kw < K; ++kw) {
            int iw = wo * S - P + kw;
            if ((unsigned)iw < (unsigned)Win)
                s += mrow[MHALF ? (iw >> 1) : iw];
        }
    }
    mc[idx] = s;
    nm[idx] = (s == 0.f) ? 0.f : 1.f;
}

// ---------------------------------------------------------------------------
// Weight transform: W[co][ci][kh][kw] f32 -> A-fragment layout bf16 hi/lo
// elem idx = (((tap*KB + kb)*COB + cob)*64 + lane)*8 + j
//   co = cob*16 + (lane&15); ci = kb*32 + (lane>>4)*8 + j; tap = kh*K+kw
// ---------------------------------------------------------------------------
__global__ void wtransform(const float* __restrict__ W, short* __restrict__ Whi,
                           short* __restrict__ Wlo, int Cout, int Cin, int Ksz,
                           size_t total) {
    size_t idx = (size_t)blockIdx.x * blockDim.x + threadIdx.x;
    if (idx >= total) return;
    int j = (int)(idx & 7);
    int lane = (int)((idx >> 3) & 63);
    size_t r = idx >> 9;
    int COB = Cout >> 4, KB = Cin >> 5;
    int cob = (int)(r % COB); r /= COB;
    int kb = (int)(r % KB);
    int tap = (int)(r / KB);
    int co = cob * 16 + (lane & 15);
    int ci = kb * 32 + (lane >> 4) * 8 + j;
    float f = W[((size_t)co * Cin + ci) * Ksz + tap];
    unsigned hi = f2bf_rne(f);
    float rr = f - bf2f(hi);
    unsigned lo = f2bf_rne(rr);
    Whi[idx] = (short)hi;
    Wlo[idx] = (short)lo;
}

// ---------------------------------------------------------------------------
// Encoder per-tap MFMA implicit-GEMM partial conv (stride 2 layers).
//   BM=128 co, BN=128 px, BK=32. 512 thr = 8 waves (4m x 2n): wave 32co x 64px.
// ---------------------------------------------------------------------------
template<int K, int S, bool AF32, int EPI>
__global__ __launch_bounds__(512) void conv_mfma(
    const void* __restrict__ Asrc, int Cin, int Hin, int Win,
    const float* __restrict__ M,
    const short* __restrict__ Whi, const short* __restrict__ Wlo,
    const float* __restrict__ mc, const float* __restrict__ bias,
    void* __restrict__ outp,
    int Hout, int Wout, int Cout)
{
    constexpr int P = (K - 1) / 2;
    __shared__ __align__(16) unsigned BH[4 * 128 * 4];   // [grp][px][4dw]
    __shared__ __align__(16) unsigned BL[4 * 128 * 4];

    const int t    = threadIdx.x;
    const int lane = t & 63;
    const int wv   = t >> 6;
    const int wm   = wv >> 1;    // 0..3
    const int wn   = wv & 1;     // 0..1
    const int img  = blockIdx.z;
    const int coB  = blockIdx.y * 128;
    const int Npix = Hout * Wout;
    const int p0   = blockIdx.x * 128;
    const int KB   = Cin >> 5;
    const int COB  = Cout >> 4;
    const size_t HW = (size_t)Hin * Win;

    // staging coords: thread stages pixel spx, channel group sg (8 ch)
    const int spx = t & 127;
    const int sg  = t >> 7;
    const int sp  = p0 + spx;
    const bool pval = sp < Npix;
    const int ho = pval ? sp / Wout : 0;
    const int wo = pval ? sp - ho * Wout : 0;

    // precompute per-tap select bits (mask & bounds) for the staging pixel
    unsigned long long selbits = 0ull;
    for (int kh = 0; kh < K; ++kh)
        for (int kw = 0; kw < K; ++kw) {
            const int ih = ho * S - P + kh;
            const int iw = wo * S - P + kw;
            bool s = false;
            if (pval && (unsigned)ih < (unsigned)Hin && (unsigned)iw < (unsigned)Win)
                s = M[(size_t)img * HW + (size_t)ih * Win + iw] != 0.f;
            selbits |= (unsigned long long)(s ? 1 : 0) << (kh * K + kw);
        }

    f32x4 acc[2][4] = {};

#pragma unroll 1
    for (int kh = 0; kh < K; ++kh)
#pragma unroll 1
    for (int kw = 0; kw < K; ++kw) {
        const int tap = kh * K + kw;
        const int ih = ho * S - P + kh;
        const int iw = wo * S - P + kw;
        const bool sel = (selbits >> tap) & 1ull;
        const size_t pix = (size_t)img * Cin * HW + (sel ? ((size_t)ih * Win + iw) : 0);
        const size_t wtap = (size_t)tap * KB;

#pragma unroll 1
        for (int kb = 0; kb < KB; ++kb) {
            const int ci0 = kb * 32 + sg * 8;
            unsigned v[8];
#pragma unroll
            for (int j = 0; j < 8; ++j) v[j] = 0u;
            if (sel) {
                if (AF32) {
                    const float* s = (const float*)Asrc + pix + (size_t)ci0 * HW;
#pragma unroll
                    for (int j = 0; j < 8; ++j) v[j] = splitpack(s[(size_t)j * HW]);
                } else {
                    const unsigned* s = (const unsigned*)Asrc + pix + (size_t)ci0 * HW;
#pragma unroll
                    for (int j = 0; j < 8; ++j) v[j] = s[(size_t)j * HW];
                }
            }
            uint4v hd, ld;
#pragma unroll
            for (int j = 0; j < 4; ++j) {
                hd[j] = (v[2 * j] & 0xFFFFu) | (v[2 * j + 1] << 16);
                ld[j] = (v[2 * j] >> 16) | (v[2 * j + 1] & 0xFFFF0000u);
            }
            *(uint4v*)&BH[(sg * 128 + spx) * 4] = hd;
            *(uint4v*)&BL[(sg * 128 + spx) * 4] = ld;
            __syncthreads();

            // A fragments: coalesced global b128 (L2/L3 resident)
            const size_t wb = ((wtap + kb) * COB + (coB >> 4) + wm * 2) * 512 + lane * 8;
            short8 ah0 = *(const short8*)(Whi + wb);
            short8 ah1 = *(const short8*)(Whi + wb + 512);
            short8 al0 = *(const short8*)(Wlo + wb);
            short8 al1 = *(const short8*)(Wlo + wb + 512);

            const int g = lane >> 4;
            const int pl = (lane & 15);
#pragma unroll
            for (int fn = 0; fn < 4; ++fn) {
                const int px = wn * 64 + fn * 16 + pl;
                short8 bh = *(const short8*)&BH[(g * 128 + px) * 4];
                short8 bl = *(const short8*)&BL[(g * 128 + px) * 4];
                acc[0][fn] = mfma16(ah0, bh, acc[0][fn]);
                acc[1][fn] = mfma16(ah1, bh, acc[1][fn]);
                acc[0][fn] = mfma16(al0, bh, acc[0][fn]);
                acc[1][fn] = mfma16(al1, bh, acc[1][fn]);
                acc[0][fn] = mfma16(ah0, bl, acc[0][fn]);
                acc[1][fn] = mfma16(ah1, bl, acc[1][fn]);
            }
            __syncthreads();
        }
    }

    // epilogue
    const float* mcb = mc + (size_t)img * Npix;
#pragma unroll
    for (int fm = 0; fm < 2; ++fm)
#pragma unroll
    for (int fn = 0; fn < 4; ++fn) {
        const int co = coB + (wm * 2 + fm) * 16 + (lane >> 4) * 4;
        const int px = p0 + wn * 64 + fn * 16 + (lane & 15);
        if (px >= Npix) continue;
        const float m = mcb[px];
        f32x4 a = acc[fm][fn];
#pragma unroll
        for (int r = 0; r < 4; ++r) {
            float y = a[r];
            if (EPI == EPI_F32_BIAS) {
                const float bv = bias[co + r];
                y = (m == 0.f) ? 0.f : (y - bv) / m + bv;
            } else {
                y = (m == 0.f) ? 0.f : y / m;
            }
            const size_t oidx = ((size_t)img * Cout + co + r) * Npix + px;
            if (EPI == EPI_PAIR_RELU) {
                y = y > 0.f ? y : 0.f;
                ((unsigned*)outp)[oidx] = splitpack(y);
            } else {
                ((float*)outp)[oidx] = y;
            }
        }
    }
}

// ---------------------------------------------------------------------------
// Decoder halo-staged 3x3 s1 p1 partial conv.
//   Output tile TH x TW; halo (TH+2)x(TW+2) x 32ch staged ONCE per K-chunk,
//   reused by all 9 taps (B traffic /9, 2 barriers per chunk).
//   A = CA half-res channels (pair, up2) then CB full-res (pair or f32 if BF32).
//   BM=128 co, 8 waves 4m x 2n: MFW=2, NFW=NF/2. Mask at half output res.
// ---------------------------------------------------------------------------
template<int TH, int TW, int NF, bool BF32, int EPI>
__global__ __launch_bounds__(512) void conv3x3(
    const void* __restrict__ Asrc, int CA, int HA, int WA,
    const void* __restrict__ Bsrc, int CB,
    const float* __restrict__ M,
    const short* __restrict__ Whi, const short* __restrict__ Wlo,
    const float* __restrict__ mc, const float* __restrict__ bias,
    void* __restrict__ outp,
    int Hout, int Wout, int Cout, int TX)
{
    constexpr int HALO_H = TH + 2, HALO_W = TW + 2, HALO = HALO_H * HALO_W;
    constexpr int NFW = NF / 2;
    constexpr int NPIX = TH * TW;
    __shared__ __align__(16) unsigned BH[4 * HALO * 4];
    __shared__ __align__(16) unsigned BL[4 * HALO * 4];

    const int t    = threadIdx.x;
    const int lane = t & 63;
    const int wv   = t >> 6;
    const int wm   = wv >> 1;    // 0..3
    const int wn   = wv & 1;     // 0..1
    const int img  = blockIdx.z;
    const int coB  = blockIdx.y * 128;
    const int tile = blockIdx.x;
    const int ty   = tile / TX;
    const int tx   = tile - ty * TX;
    const int oy0  = ty * TH, ox0 = tx * TW;
    const int Cin  = CA + CB;
    const int KB   = Cin >> 5;
    const int COB  = Cout >> 4;
    const int WM   = Wout >> 1;
    const size_t HWA = (size_t)HA * WA;
    const size_t HWB = (size_t)Hout * Wout;

    // staging precompute (pixel = t when t < HALO)
    bool sel = false;
    size_t abase = 0, bbase = 0;
    if (t < HALO) {
        const int hy = t / HALO_W, hx = t - hy * HALO_W;
        const int iy = oy0 - 1 + hy, ix = ox0 - 1 + hx;
        if ((unsigned)iy < (unsigned)Hout && (unsigned)ix < (unsigned)Wout) {
            sel = M[((size_t)img * (Hout >> 1) + (iy >> 1)) * WM + (ix >> 1)] != 0.f;
            if (sel) {
                abase = (size_t)img * CA * HWA + (size_t)(iy >> 1) * WA + (ix >> 1);
                bbase = (size_t)img * CB * HWB + (size_t)iy * Wout + ix;
            }
        }
    }

    f32x4 acc[2][NFW] = {};
    const size_t wstride = (size_t)KB * COB * 512;

#pragma unroll 1
    for (int kb = 0; kb < KB; ++kb) {
        // ---- stage halo tile (masked input, split to bf16 hi/lo) ----
        if (t < HALO) {
            const int ci0 = kb * 32;
#pragma unroll
            for (int g = 0; g < 4; ++g) {
                const int c = ci0 + g * 8;
                unsigned v[8];
#pragma unroll
                for (int j = 0; j < 8; ++j) v[j] = 0u;
                if (sel) {
                    if (c < CA) {
                        const unsigned* s = (const unsigned*)Asrc + abase + (size_t)c * HWA;
#pragma unroll
                        for (int j = 0; j < 8; ++j) v[j] = s[(size_t)j * HWA];
                    } else {
                        if (BF32) {
                            const float* s = (const float*)Bsrc + bbase + (size_t)(c - CA) * HWB;
#pragma unroll
                            for (int j = 0; j < 8; ++j) v[j] = splitpack(s[(size_t)j * HWB]);
                        } else {
                            const unsigned* s = (const unsigned*)Bsrc + bbase + (size_t)(c - CA) * HWB;
#pragma unroll
                            for (int j = 0; j < 8; ++j) v[j] = s[(size_t)j * HWB];
                        }
                    }
                }
                uint4v hd, ld;
#pragma unroll
                for (int j = 0; j < 4; ++j) {
                    hd[j] = (v[2 * j] & 0xFFFFu) | (v[2 * j + 1] << 16);
                    ld[j] = (v[2 * j] >> 16) | (v[2 * j + 1] & 0xFFFF0000u);
                }
                *(uint4v*)&BH[(g * HALO + t) * 4] = hd;
                *(uint4v*)&BL[(g * HALO + t) * 4] = ld;
            }
        }
        __syncthreads();

        // ---- 9 taps from LDS, A prefetched one tap ahead ----
        size_t wb = ((size_t)kb * COB + (coB >> 4) + wm * 2) * 512 + lane * 8;
        short8 ah0 = *(const short8*)(Whi + wb);
        short8 ah1 = *(const short8*)(Whi + wb + 512);
        short8 al0 = *(const short8*)(Wlo + wb);
        short8 al1 = *(const short8*)(Wlo + wb + 512);

        const int g = lane >> 4;
        const int pl = lane & 15;
        int dh = 0, dw = 0;
#pragma unroll 1
        for (int tap = 0; tap < 9; ++tap) {
            const size_t wbn = wb + ((tap < 8) ? wstride : 0);
            short8 nh0 = *(const short8*)(Whi + wbn);
            short8 nh1 = *(const short8*)(Whi + wbn + 512);
            short8 nl0 = *(const short8*)(Wlo + wbn);
            short8 nl1 = *(const short8*)(Wlo + wbn + 512);

#pragma unroll
            for (int fn = 0; fn < NFW; ++fn) {
                int pxf = (wn * NFW + fn) * 16 + pl;
                pxf = pxf < NPIX ? pxf : NPIX - 1;
                const int oy = pxf / TW, ox = pxf - oy * TW;
                const int hpx = (oy + dh) * HALO_W + (ox + dw);
                short8 bh = *(const short8*)&BH[(g * HALO + hpx) * 4];
                short8 bl = *(const short8*)&BL[(g * HALO + hpx) * 4];
                acc[0][fn] = mfma16(ah0, bh, acc[0][fn]);
                acc[1][fn] = mfma16(ah1, bh, acc[1][fn]);
                acc[0][fn] = mfma16(al0, bh, acc[0][fn]);
                acc[1][fn] = mfma16(al1, bh, acc[1][fn]);
                acc[0][fn] = mfma16(ah0, bl, acc[0][fn]);
                acc[1][fn] = mfma16(ah1, bl, acc[1][fn]);
            }
            ah0 = nh0; ah1 = nh1; al0 = nl0; al1 = nl1;
            wb = wbn;
            if (++dw == 3) { dw = 0; ++dh; }
        }
        __syncthreads();
    }

    // ---- epilogue: renorm by mc, optional bias, store f32 ----
    const float* mcb = mc + (size_t)img * HWB;
#pragma unroll
    for (int fm = 0; fm < 2; ++fm)
#pragma unroll
    for (int fn = 0; fn < NFW; ++fn) {
        const int co = coB + (wm * 2 + fm) * 16 + (lane >> 4) * 4;
        const int pxf = (wn * NFW + fn) * 16 + (lane & 15);
        if (pxf >= NPIX) continue;
        const int oy = pxf / TW, ox = pxf - oy * TW;
        const int gy = oy0 + oy, gx = ox0 + ox;
        const float m = mcb[(size_t)gy * Wout + gx];
        f32x4 a = acc[fm][fn];
#pragma unroll
        for (int r = 0; r < 4; ++r) {
            float y = a[r];
            if (EPI == EPI_F32_BIAS) {
                const float bv = bias[co + r];
                y = (m == 0.f) ? 0.f : (y - bv) / m + bv;
            } else {
                y = (m == 0.f) ? 0.f : y / m;
            }
            ((float*)outp)[((size_t)img * Cout + co + r) * HWB + (size_t)gy * Wout + gx] = y;
        }
    }
}

// ---------------------------------------------------------------------------
// BatchNorm (training-mode, biased var over N,H,W)
// ---------------------------------------------------------------------------
__global__ __launch_bounds__(256) void bn_stats_kernel(const float* __restrict__ y,
                                                       int N, int C, int HW,
                                                       float* __restrict__ mean,
                                                       float* __restrict__ istd) {
    const int c = blockIdx.x;
    double s = 0.0, s2 = 0.0;
    const int tot = N * HW;
    for (int i = threadIdx.x; i < tot; i += blockDim.x) {
        int n = i / HW, hw = i - n * HW;
        float v = y[((size_t)n * C + c) * HW + hw];
        s += v;
        s2 += (double)v * v;
    }
    __shared__ double sh[256], sh2[256];
    sh[threadIdx.x] = s; sh2[threadIdx.x] = s2;
    __syncthreads();
    for (int o = 128; o > 0; o >>= 1) {
        if (threadIdx.x < o) { sh[threadIdx.x] += sh[threadIdx.x + o]; sh2[threadIdx.x] += sh2[threadIdx.x + o]; }
        __syncthreads();
    }
    if (threadIdx.x == 0) {
        double mu = sh[0] / tot;
        double var = sh2[0] / tot - mu * mu;
        mean[c] = (float)mu;
        istd[c] = (float)(1.0 / sqrt(var + 1e-5));
    }
}

// BN apply + act; writes packed bf16-pair (and optional f32 copy)
__global__ void bn_apply_pair(const float* __restrict__ y,
                              const float* __restrict__ mean, const float* __restrict__ istd,
                              const float* __restrict__ g, const float* __restrict__ b,
                              unsigned* __restrict__ pout, float* __restrict__ fout,
                              int C, int HW, int total, int act) {
    int idx = blockIdx.x * blockDim.x + threadIdx.x;
    if (idx >= total) return;
    int c = (idx / HW) % C;
    float v = (y[idx] - mean[c]) * istd[c] * g[c] + b[c];
    v = actf(v, act);
    pout[idx] = splitpack(v);
    if (fout) fout[idx] = v;
}

// ---------------------------------------------------------------------------
// NLM feature swapping at h2 (B=8, C=512, Npix=1296)
// ---------------------------------------------------------------------------
#define NLM_C 512
#define NLM_N 1296

__global__ void nlm_prep_kernel(const float* __restrict__ h2, float* __restrict__ xT,
                                int Bn, int C, int Npix) {
    size_t idx = (size_t)blockIdx.x * blockDim.x + threadIdx.x;
    size_t total = (size_t)Bn * Npix * C;
    if (idx >= total) return;
    int c = (int)(idx % C);
    size_t t = idx / C;
    int j = (int)(t % Npix);
    int b = (int)(t / Npix);
    xT[idx] = h2[((size_t)b * C + c) * Npix + j];
}

__global__ void nlm_sq_kernel(const float* __restrict__ xT, float* __restrict__ sq,
                              int BN, int C) {
    int idx = blockIdx.x * blockDim.x + threadIdx.x;
    if (idx >= BN) return;
    const float* r = xT + (size_t)idx * C;
    float s = 0.f;
    for (int c = 0; c < C; ++c) s = fmaf(r[c], r[c], s);
    sq[idx] = s;
}

__global__ __launch_bounds__(256) void nlm_kernel(
    const float* __restrict__ xT, const float* __restrict__ sq,
    const float* __restrict__ mask,
    unsigned* __restrict__ out,     // packed bf16-pair h2s, NCHW
    float inv_h2) {
    const int i = blockIdx.x;
    const int b = blockIdx.y;
    const int tid = threadIdx.x;
    if (mask[(size_t)b * NLM_N + i] > 0.5f) return;  // background: keep pair written by bn_apply

    __shared__ float Drow[NLM_N];
    __shared__ float xi[NLM_C];
    __shared__ float red[256];

    const float* xib = xT + ((size_t)b * NLM_N + i) * NLM_C;
    for (int c = tid; c < NLM_C; c += 256) xi[c] = xib[c];
    __syncthreads();

    const float sqi = sq[(size_t)b * NLM_N + i];
    const float BIG = 3.4e38f;
    float lmin = BIG;
    for (int j = tid; j < NLM_N; j += 256) {
        float d = BIG;
        if (mask[(size_t)b * NLM_N + j] > 0.5f) {
            const float* xj = xT + ((size_t)b * NLM_N + j) * NLM_C;
            float dot = 0.f;
            for (int c = 0; c < NLM_C; ++c) dot = fmaf(xi[c], xj[c], dot);
            d = sqi + sq[(size_t)b * NLM_N + j] - 2.f * dot;
            d = d > 0.f ? d : 0.f;
            lmin = d < lmin ? d : lmin;
        }
        Drow[j] = d;
    }
    red[tid] = lmin;
    __syncthreads();
    for (int o = 128; o > 0; o >>= 1) {
        if (tid < o) red[tid] = fminf(red[tid], red[tid + o]);
        __syncthreads();
    }
    const float dmin = red[0];
    __syncthreads();

    float lsum = 0.f;
    for (int j = tid; j < NLM_N; j += 256) {
        float wv = 0.f;
        if (Drow[j] < 3.3e38f) wv = expf(-(Drow[j] - dmin) * inv_h2);
        Drow[j] = wv;
        lsum += wv;
    }
    red[tid] = lsum;
    __syncthreads();
    for (int o = 128; o > 0; o >>= 1) {
        if (tid < o) red[tid] += red[tid + o];
        __syncthreads();
    }
    const float invw = 1.f / red[0];
    __syncthreads();

    for (int c = tid; c < NLM_C; c += 256) {
        float a = 0.f;
        for (int j = 0; j < NLM_N; ++j)
            a = fmaf(Drow[j], xT[((size_t)b * NLM_N + j) * NLM_C + c], a);
        out[((size_t)b * NLM_C + c) * NLM_N + i] = splitpack(a * invw);
    }
}

// ---------------------------------------------------------------------------
// Driver
// ---------------------------------------------------------------------------
extern "C" void kernel_launch(void* const* d_in, const int* in_sizes, int n_in,
                              void* d_out, int out_size, void* d_ws, size_t ws_size,
                              hipStream_t stream) {
    const float* x0    = (const float*)d_in[0];
    const float* m0    = (const float*)d_in[1];
    const float* Wsrc[8] = {
        (const float*)d_in[2], (const float*)d_in[3], (const float*)d_in[4],
        (const float*)d_in[5], (const float*)d_in[6], (const float*)d_in[7],
        (const float*)d_in[8], (const float*)d_in[9]
    };
    const float* dec1b = (const float*)d_in[10];
    const float* enc2g = (const float*)d_in[11];
    const float* enc2b = (const float*)d_in[12];
    const float* enc3g = (const float*)d_in[13];
    const float* enc3b = (const float*)d_in[14];
    const float* enc4g = (const float*)d_in[15];
    const float* enc4b = (const float*)d_in[16];
    const float* dec4g = (const float*)d_in[17];
    const float* dec4b = (const float*)d_in[18];
    const float* dec3g = (const float*)d_in[19];
    const float* dec3b = (const float*)d_in[20];
    const float* dec2g = (const float*)d_in[21];
    const float* dec2b = (const float*)d_in[22];
    float* outp = (float*)d_out;

    const int N = 8;
    float* ws = (float*)d_ws;
    size_t off = 0;
    auto alloc = [&](size_t nf) {
        size_t o = off;
        off += ((nf + 63) / 64) * 64;
        return ws + o;
    };

    unsigned* h1pair  = (unsigned*)alloc(10616832);  // 8x256x72x72  (later d2pair)
    unsigned* h2spair = (unsigned*)alloc(5308416);   // 8x512x36x36  (later d3pair)
    unsigned* h3pair  = (unsigned*)alloc(1327104);   // 8x512x18x18
    unsigned* h4pair  = (unsigned*)alloc(331776);    // 8x512x9x9
    unsigned* d4pair  = (unsigned*)alloc(1327104);
    float* ybuf = alloc(10616832);                   // pre-BN f32 scratch (max dec2)
    float* h2f  = alloc(5308416);                    // f32 h2 for NLM
    float* xT   = alloc(5308416);
    float* sqb  = alloc(10368);
    float* mc   = alloc(165888);
    float* nm1  = alloc(41472);
    float* nm2  = alloc(10368);
    float* nm3  = alloc(2592);
    float* nm4  = alloc(648);
    float* nmd4 = alloc(2592);
    float* nmd3 = alloc(10368);
    float* nmd2 = alloc(41472);
    float* nmx  = alloc(165888);
    float* bmean = alloc(512);
    float* bistd = alloc(512);
    short* Whi = (short*)alloc(10625024);            // 21,250,048 bf16
    short* Wlo = (short*)alloc(10625024);
    unsigned* d3pair = h2spair;  // h2spair dead after dec3 conv
    unsigned* d2pair = h1pair;   // h1pair dead after dec2 conv

    if (ws_size < off * sizeof(float)) return;  // workspace too small; fail loudly

    auto cdiv = [](size_t a, size_t b) { return (int)((a + b - 1) / b); };

    // ---- weight transforms (A-fragment layout, bf16 hi/lo) ----
    struct WLay { int Cout, Cin, K; size_t ofs; };
    const WLay WL[8] = {
        {256, 128, 7, 0},         // enc1
        {512, 256, 5, 1605632},   // enc2
        {512, 512, 3, 4882432},   // enc3
        {512, 512, 3, 7241728},   // enc4
        {512, 1024, 3, 9601024},  // dec4
        {512, 1024, 3, 14319616}, // dec3
        {256, 768, 3, 19038208},  // dec2
        {128, 384, 3, 20807680},  // dec1
    };
    for (int i = 0; i < 8; ++i) {
        size_t tot = (size_t)WL[i].Cout * WL[i].Cin * WL[i].K * WL[i].K;
        wtransform<<<cdiv(tot, 256), 256, 0, stream>>>(
            Wsrc[i], Whi + WL[i].ofs, Wlo + WL[i].ofs, WL[i].Cout, WL[i].Cin,
            WL[i].K * WL[i].K, tot);
    }

    // ---------------- enc1: 128->256, 7x7 s2 p3, relu, no BN ----------------
    maskconv_kernel<7, 2, false><<<cdiv(N * 72 * 72, 256), 256, 0, stream>>>(
        m0, 144, 144, mc, nm1, N, 144, 144, 72, 72);
    conv_mfma<7, 2, true, EPI_PAIR_RELU><<<dim3(41, 2, N), 512, 0, stream>>>(
        x0, 128, 144, 144, m0,
        Whi + WL[0].ofs, Wlo + WL[0].ofs, mc, nullptr, h1pair,
        72, 72, 256);

    // ---------------- enc2: 256->512, 5x5 s2 p2, BN+relu ----------------
    maskconv_kernel<5, 2, false><<<cdiv(N * 36 * 36, 256), 256, 0, stream>>>(
        nm1, 72, 72, mc, nm2, N, 72, 72, 36, 36);
    conv_mfma<5, 2, false, EPI_F32><<<dim3(11, 4, N), 512, 0, stream>>>(
        h1pair, 256, 72, 72, nm1,
        Whi + WL[1].ofs, Wlo + WL[1].ofs, mc, nullptr, ybuf,
        36, 36, 512);
    bn_stats_kernel<<<512, 256, 0, stream>>>(ybuf, N, 512, 1296, bmean, bistd);
    bn_apply_pair<<<cdiv(5308416, 256), 256, 0, stream>>>(
        ybuf, bmean, bistd, enc2g, enc2b, h2spair, h2f, 512, 1296, 5308416, ACT_RELU);

    // ---------------- NLM swap at h2 ----------------
    nlm_prep_kernel<<<cdiv(5308416, 256), 256, 0, stream>>>(h2f, xT, N, 512, 1296);
    nlm_sq_kernel<<<cdiv(N * 1296, 256), 256, 0, stream>>>(xT, sqb, N * 1296, 512);
    nlm_kernel<<<dim3(1296, N), 256, 0, stream>>>(xT, sqb, nm2, h2spair, 1.f / 25.f);

    // ---------------- enc3: 512->512, 3x3 s2 p1, BN+relu ----------------
    maskconv_kernel<3, 2, false><<<cdiv(N * 18 * 18, 256), 256, 0, stream>>>(
        nm2, 36, 36, mc, nm3, N, 36, 36, 18, 18);
    conv_mfma<3, 2, false, EPI_F32><<<dim3(3, 4, N), 512, 0, stream>>>(
        h2spair, 512, 36, 36, nm2,
        Whi + WL[2].ofs, Wlo + WL[2].ofs, mc, nullptr, ybuf,
        18, 18, 512);
    bn_stats_kernel<<<512, 256, 0, stream>>>(ybuf, N, 512, 324, bmean, bistd);
    bn_apply_pair<<<cdiv(1327104, 256), 256, 0, stream>>>(
        ybuf, bmean, bistd, enc3g, enc3b, h3pair, nullptr, 512, 324, 1327104, ACT_RELU);

    // ---------------- enc4: 512->512, 3x3 s2 p1, BN+relu ----------------
    maskconv_kernel<3, 2, false><<<cdiv(N * 9 * 9, 256), 256, 0, stream>>>(
        nm3, 18, 18, mc, nm4, N, 18, 18, 9, 9);
    conv_mfma<3, 2, false, EPI_F32><<<dim3(1, 4, N), 512, 0, stream>>>(
        h3pair, 512, 18, 18, nm3,
        Whi + WL[3].ofs, Wlo + WL[3].ofs, mc, nullptr, ybuf,
        9, 9, 512);
    bn_stats_kernel<<<512, 256, 0, stream>>>(ybuf, N, 512, 81, bmean, bistd);
    bn_apply_pair<<<cdiv(331776, 256), 256, 0, stream>>>(
        ybuf, bmean, bistd, enc4g, enc4b, h4pair, nullptr, 512, 81, 331776, ACT_RELU);

    // ---------------- dec4: cat[up2(h4), h3] 1024->512 @18, BN+leaky ----------------
    maskconv_kernel<3, 1, true><<<cdiv(N * 18 * 18, 256), 256, 0, stream>>>(
        nm4, 9, 9, mc, nmd4, N, 18, 18, 18, 18);
    conv3x3<9, 18, 12, false, EPI_F32><<<dim3(2, 4, N), 512, 0, stream>>>(
        h4pair, 512, 9, 9, h3pair, 512, nm4,
        Whi + WL[4].ofs, Wlo + WL[4].ofs, mc, nullptr, ybuf,
        18, 18, 512, 1);
    bn_stats_kernel<<<512, 256, 0, stream>>>(ybuf, N, 512, 324, bmean, bistd);
    bn_apply_pair<<<cdiv(1327104, 256), 256, 0, stream>>>(
        ybuf, bmean, bistd, dec4g, dec4b, d4pair, nullptr, 512, 324, 1327104, ACT_LEAKY);

    // ---------------- dec3: cat[up2(d4), h2s] 1024->512 @36, BN+leaky ----------------
    maskconv_kernel<3, 1, true><<<cdiv(N * 36 * 36, 256), 256, 0, stream>>>(
        nmd4, 18, 18, mc, nmd3, N, 36, 36, 36, 36);
    conv3x3<12, 18, 14, false, EPI_F32><<<dim3(6, 4, N), 512, 0, stream>>>(
        d4pair, 512, 18, 18, h2spair, 512, nmd4,
        Whi + WL[5].ofs, Wlo + WL[5].ofs, mc, nullptr, ybuf,
        36, 36, 512, 2);
    bn_stats_kernel<<<512, 256, 0, stream>>>(ybuf, N, 512, 1296, bmean, bistd);
    bn_apply_pair<<<cdiv(5308416, 256), 256, 0, stream>>>(
        ybuf, bmean, bistd, dec3g, dec3b, d3pair, nullptr, 512, 1296, 5308416, ACT_LEAKY);

    // ---------------- dec2: cat[up2(d3), h1] 768->256 @72, BN+leaky ----------------
    maskconv_kernel<3, 1, true><<<cdiv(N * 72 * 72, 256), 256, 0, stream>>>(
        nmd3, 36, 36, mc, nmd2, N, 72, 72, 72, 72);
    conv3x3<12, 24, 18, false, EPI_F32><<<dim3(18, 2, N), 512, 0, stream>>>(
        d3pair, 512, 36, 36, h1pair, 256, nmd3,
        Whi + WL[6].ofs, Wlo + WL[6].ofs, mc, nullptr, ybuf,
        72, 72, 256, 3);
    bn_stats_kernel<<<256, 256, 0, stream>>>(ybuf, N, 256, 5184, bmean, bistd);
    bn_apply_pair<<<cdiv(10616832, 256), 256, 0, stream>>>(
        ybuf, bmean, bistd, dec2g, dec2b, d2pair, nullptr, 256, 5184, 10616832, ACT_LEAKY);

    // ---------------- dec1: cat[up2(d2), x0] 384->128 @144, bias, no BN/act ----------------
    maskconv_kernel<3, 1, true><<<cdiv(N * 144 * 144, 256), 256, 0, stream>>>(
        nmd2, 72, 72, mc, nmx, N, 144, 144, 144, 144);
    conv3x3<16, 16, 16, true, EPI_F32_BIAS><<<dim3(81, 1, N), 512, 0, stream>>>(
        d2pair, 256, 72, 72, x0, 128, nmd2,
        Whi + WL[7].ofs, Wlo + WL[7].ofs, mc, dec1b, outp,
        144, 144, 128, 9);
}

// Round 4
// 3515.484 us; speedup vs baseline: 87.2526x; 1.3837x over previous
//
#include <hip/hip_runtime.h>
#include <math.h>

#define ACT_NONE 0
#define ACT_RELU 1
#define ACT_LEAKY 2

#define EPI_F32 0
#define EPI_PAIR_RELU 1
#define EPI_F32_BIAS 2

typedef __attribute__((ext_vector_type(8))) short short8;
typedef __attribute__((ext_vector_type(8))) __bf16 bf16x8;
typedef __attribute__((ext_vector_type(4))) float f32x4;
typedef __attribute__((ext_vector_type(4))) unsigned uint4v;

__device__ __forceinline__ float actf(float y, int act) {
    if (act == ACT_RELU)  return y > 0.f ? y : 0.f;
    if (act == ACT_LEAKY) return y >= 0.f ? y : 0.2f * y;
    return y;
}

// ---- bf16 split helpers: f32 -> (hi,lo) bf16 pair packed in u32 (hi in low 16) ----
__device__ __forceinline__ unsigned f2bf_rne(float f) {
    unsigned u = __float_as_uint(f);
    return (u + 0x7FFFu + ((u >> 16) & 1u)) >> 16;
}
__device__ __forceinline__ float bf2f(unsigned h) { return __uint_as_float(h << 16); }
__device__ __forceinline__ unsigned splitpack(float f) {
    unsigned hi = f2bf_rne(f);
    float r = f - bf2f(hi);
    unsigned lo = f2bf_rne(r);
    return (hi & 0xFFFFu) | (lo << 16);
}

__device__ __forceinline__ f32x4 mfma16(short8 a, short8 b, f32x4 c) {
    return __builtin_amdgcn_mfma_f32_16x16x32_bf16(
        __builtin_bit_cast(bf16x8, a), __builtin_bit_cast(bf16x8, b), c, 0, 0, 0);
}

// ---------------------------------------------------------------------------
// Mask convolution: mc = conv(mask, ones(K,K), stride S, pad P); nm = (mc!=0)
// ---------------------------------------------------------------------------
template<int K, int S, bool MHALF>
__global__ void maskconv_kernel(const float* __restrict__ M, int HM, int WM,
                                float* __restrict__ mc, float* __restrict__ nm,
                                int N, int Hin, int Win, int Hout, int Wout) {
    constexpr int P = (K - 1) / 2;
    int idx = blockIdx.x * blockDim.x + threadIdx.x;
    int total = N * Hout * Wout;
    if (idx >= total) return;
    int wo = idx % Wout;
    int t  = idx / Wout;
    int ho = t % Hout;
    int n  = t / Hout;
    float s = 0.f;
    for (int kh = 0; kh < K; ++kh) {
        int ih = ho * S - P + kh;
        if ((unsigned)ih >= (unsigned)Hin) continue;
        const float* mrow = M + ((size_t)n * HM + (MHALF ? (ih >> 1) : ih)) * WM;
        for (int kw = 0; kw < K; ++kw) {
            int iw = wo * S - P + kw;
            if ((unsigned)iw < (unsigned)Win)
                s += mrow[MHALF ? (iw >> 1) : iw];
        }
    }
    mc[idx] = s;
    nm[idx] = (s == 0.f) ? 0.f : 1.f;
}

// ---------------------------------------------------------------------------
// Weight transform: W[co][ci][kh][kw] f32 -> A-fragment layout bf16 hi/lo
// elem idx = (((tap*KB + kb)*COB + cob)*64 + lane)*8 + j
//   co = cob*16 + (lane&15); ci = kb*32 + (lane>>4)*8 + j; tap = kh*K+kw
// ---------------------------------------------------------------------------
__global__ void wtransform(const float* __restrict__ W, short* __restrict__ Whi,
                           short* __restrict__ Wlo, int Cout, int Cin, int Ksz,
                           size_t total) {
    size_t idx = (size_t)blockIdx.x * blockDim.x + threadIdx.x;
    if (idx >= total) return;
    int j = (int)(idx & 7);
    int lane = (int)((idx >> 3) & 63);
    size_t r = idx >> 9;
    int COB = Cout >> 4, KB = Cin >> 5;
    int cob = (int)(r % COB); r /= COB;
    int kb = (int)(r % KB);
    int tap = (int)(r / KB);
    int co = cob * 16 + (lane & 15);
    int ci = kb * 32 + (lane >> 4) * 8 + j;
    float f = W[((size_t)co * Cin + ci) * Ksz + tap];
    unsigned hi = f2bf_rne(f);
    float rr = f - bf2f(hi);
    unsigned lo = f2bf_rne(rr);
    Whi[idx] = (short)hi;
    Wlo[idx] = (short)lo;
}

// ---------------------------------------------------------------------------
// Encoder halo-staged stride-S conv (full K*K tap reuse from LDS).
//   Out tile TH x TW; halo ((TH-1)S+K) x ((TW-1)S+K) x 32ch staged once per kb.
//   BM=256 co per block (blockIdx.y), 8 waves = 4m x 2n; wave = 64co x NFW*16px.
//   Mask at input resolution. 3-product bf16x2 split.
// ---------------------------------------------------------------------------
template<int K, int S, int TH, int TW, int NFW, bool AF32, int EPI>
__global__ __launch_bounds__(512) void conv_enc(
    const void* __restrict__ Asrc, int Cin, int Hin, int Win,
    const float* __restrict__ M,
    const short* __restrict__ Whi, const short* __restrict__ Wlo,
    const float* __restrict__ mc, const float* __restrict__ bias,
    void* __restrict__ outp,
    int Hout, int Wout, int Cout, int TX)
{
    constexpr int P = (K - 1) / 2;
    constexpr int HH  = (TH - 1) * S + K;
    constexpr int HWC = (TW - 1) * S + K;
    constexpr int PXC = HH * HWC;
    __shared__ __align__(16) unsigned BH[4 * PXC * 4];
    __shared__ __align__(16) unsigned BL[4 * PXC * 4];

    const int t    = threadIdx.x;
    const int lane = t & 63;
    const int wv   = t >> 6;
    const int wm   = wv >> 1;    // 0..3 : 64-co slice
    const int wn   = wv & 1;     // 0..1 : px half
    const int img  = blockIdx.z;
    const int coB  = blockIdx.y * 256;
    const int tile = blockIdx.x;
    const int ty   = tile / TX, tx = tile - ty * TX;
    const int oy0  = ty * TH, ox0 = tx * TW;
    const int KB   = Cin >> 5;
    const int COB  = Cout >> 4;
    const size_t HW = (size_t)Hin * Win;
    const int g  = lane >> 4;
    const int pl = lane & 15;

    f32x4 acc[4][NFW] = {};

#pragma unroll 1
    for (int kb = 0; kb < KB; ++kb) {
        // ---- stage halo (masked input, split bf16 hi/lo) ----
        for (int q = t; q < PXC; q += 512) {
            const int r = q / HWC, c = q - r * HWC;
            const int iy = oy0 * S - P + r;
            const int ix = ox0 * S - P + c;
            bool sel = (unsigned)iy < (unsigned)Hin && (unsigned)ix < (unsigned)Win;
            size_t base = 0;
            if (sel) {
                sel = M[(size_t)img * HW + (size_t)iy * Win + ix] != 0.f;
                base = (size_t)img * Cin * HW + (size_t)iy * Win + ix;
            }
#pragma unroll
            for (int gg = 0; gg < 4; ++gg) {
                const int c0 = kb * 32 + gg * 8;
                unsigned v[8];
#pragma unroll
                for (int j = 0; j < 8; ++j) v[j] = 0u;
                if (sel) {
                    if (AF32) {
                        const float* s = (const float*)Asrc + base + (size_t)c0 * HW;
#pragma unroll
                        for (int j = 0; j < 8; ++j) v[j] = splitpack(s[(size_t)j * HW]);
                    } else {
                        const unsigned* s = (const unsigned*)Asrc + base + (size_t)c0 * HW;
#pragma unroll
                        for (int j = 0; j < 8; ++j) v[j] = s[(size_t)j * HW];
                    }
                }
                uint4v hd, ld;
#pragma unroll
                for (int j = 0; j < 4; ++j) {
                    hd[j] = (v[2 * j] & 0xFFFFu) | (v[2 * j + 1] << 16);
                    ld[j] = (v[2 * j] >> 16) | (v[2 * j + 1] & 0xFFFF0000u);
                }
                *(uint4v*)&BH[(gg * PXC + q) * 4] = hd;
                *(uint4v*)&BL[(gg * PXC + q) * 4] = ld;
            }
        }
        __syncthreads();

        // ---- all K*K taps from LDS ----
#pragma unroll 1
        for (int kh = 0; kh < K; ++kh)
#pragma unroll 1
        for (int kw = 0; kw < K; ++kw) {
            const int tap = kh * K + kw;
            const size_t wb = (((size_t)tap * KB + kb) * COB + (coB >> 4) + wm * 4) * 512
                            + (size_t)lane * 8;
            short8 ah[4], al[4];
#pragma unroll
            for (int fm = 0; fm < 4; ++fm) {
                ah[fm] = *(const short8*)(Whi + wb + (size_t)fm * 512);
                al[fm] = *(const short8*)(Wlo + wb + (size_t)fm * 512);
            }
#pragma unroll
            for (int fn = 0; fn < NFW; ++fn) {
                const int pxf = (wn * NFW + fn) * 16 + pl;
                const int oy = pxf / TW, ox = pxf - oy * TW;
                const int h = (oy * S + kh) * HWC + ox * S + kw;
                short8 bh = *(const short8*)&BH[(g * PXC + h) * 4];
                short8 bl = *(const short8*)&BL[(g * PXC + h) * 4];
#pragma unroll
                for (int fm = 0; fm < 4; ++fm) {
                    acc[fm][fn] = mfma16(ah[fm], bh, acc[fm][fn]);
                    acc[fm][fn] = mfma16(al[fm], bh, acc[fm][fn]);
                    acc[fm][fn] = mfma16(ah[fm], bl, acc[fm][fn]);
                }
            }
        }
        __syncthreads();
    }

    // ---- epilogue: renorm by mc, store ----
    const int Npix = Hout * Wout;
    const float* mcb = mc + (size_t)img * Npix;
#pragma unroll
    for (int fm = 0; fm < 4; ++fm)
#pragma unroll
    for (int fn = 0; fn < NFW; ++fn) {
        const int co = coB + (wm * 4 + fm) * 16 + (lane >> 4) * 4;
        const int pxf = (wn * NFW + fn) * 16 + (lane & 15);
        const int oy = pxf / TW, ox = pxf - oy * TW;
        const int gy = oy0 + oy, gx = ox0 + ox;
        if (gy >= Hout || gx >= Wout) continue;
        const float m = mcb[(size_t)gy * Wout + gx];
        f32x4 a = acc[fm][fn];
#pragma unroll
        for (int r = 0; r < 4; ++r) {
            float y = a[r];
            if (EPI == EPI_F32_BIAS) {
                const float bv = bias[co + r];
                y = (m == 0.f) ? 0.f : (y - bv) / m + bv;
            } else {
                y = (m == 0.f) ? 0.f : y / m;
            }
            const size_t oidx = ((size_t)img * Cout + co + r) * Npix + (size_t)gy * Wout + gx;
            if (EPI == EPI_PAIR_RELU) {
                y = y > 0.f ? y : 0.f;
                ((unsigned*)outp)[oidx] = splitpack(y);
            } else {
                ((float*)outp)[oidx] = y;
            }
        }
    }
}

// ---------------------------------------------------------------------------
// Decoder halo-staged 3x3 s1 p1 partial conv (as round 3, retiled).
// ---------------------------------------------------------------------------
template<int TH, int TW, int NF, bool BF32, int EPI>
__global__ __launch_bounds__(512) void conv3x3(
    const void* __restrict__ Asrc, int CA, int HA, int WA,
    const void* __restrict__ Bsrc, int CB,
    const float* __restrict__ M,
    const short* __restrict__ Whi, const short* __restrict__ Wlo,
    const float* __restrict__ mc, const float* __restrict__ bias,
    void* __restrict__ outp,
    int Hout, int Wout, int Cout, int TX)
{
    constexpr int HALO_H = TH + 2, HALO_W = TW + 2, HALO = HALO_H * HALO_W;
    constexpr int NFW = NF / 2;
    constexpr int NPIX = TH * TW;
    __shared__ __align__(16) unsigned BH[4 * HALO * 4];
    __shared__ __align__(16) unsigned BL[4 * HALO * 4];

    const int t    = threadIdx.x;
    const int lane = t & 63;
    const int wv   = t >> 6;
    const int wm   = wv >> 1;    // 0..3
    const int wn   = wv & 1;     // 0..1
    const int img  = blockIdx.z;
    const int coB  = blockIdx.y * 128;
    const int tile = blockIdx.x;
    const int ty   = tile / TX;
    const int tx   = tile - ty * TX;
    const int oy0  = ty * TH, ox0 = tx * TW;
    const int Cin  = CA + CB;
    const int KB   = Cin >> 5;
    const int COB  = Cout >> 4;
    const int WM   = Wout >> 1;
    const size_t HWA = (size_t)HA * WA;
    const size_t HWB = (size_t)Hout * Wout;

    bool sel = false;
    size_t abase = 0, bbase = 0;
    if (t < HALO) {
        const int hy = t / HALO_W, hx = t - hy * HALO_W;
        const int iy = oy0 - 1 + hy, ix = ox0 - 1 + hx;
        if ((unsigned)iy < (unsigned)Hout && (unsigned)ix < (unsigned)Wout) {
            sel = M[((size_t)img * (Hout >> 1) + (iy >> 1)) * WM + (ix >> 1)] != 0.f;
            if (sel) {
                abase = (size_t)img * CA * HWA + (size_t)(iy >> 1) * WA + (ix >> 1);
                bbase = (size_t)img * CB * HWB + (size_t)iy * Wout + ix;
            }
        }
    }

    f32x4 acc[2][NFW] = {};
    const size_t wstride = (size_t)KB * COB * 512;

#pragma unroll 1
    for (int kb = 0; kb < KB; ++kb) {
        if (t < HALO) {
            const int ci0 = kb * 32;
#pragma unroll
            for (int g = 0; g < 4; ++g) {
                const int c = ci0 + g * 8;
                unsigned v[8];
#pragma unroll
                for (int j = 0; j < 8; ++j) v[j] = 0u;
                if (sel) {
                    if (c < CA) {
                        const unsigned* s = (const unsigned*)Asrc + abase + (size_t)c * HWA;
#pragma unroll
                        for (int j = 0; j < 8; ++j) v[j] = s[(size_t)j * HWA];
                    } else {
                        if (BF32) {
                            const float* s = (const float*)Bsrc + bbase + (size_t)(c - CA) * HWB;
#pragma unroll
                            for (int j = 0; j < 8; ++j) v[j] = splitpack(s[(size_t)j * HWB]);
                        } else {
                            const unsigned* s = (const unsigned*)Bsrc + bbase + (size_t)(c - CA) * HWB;
#pragma unroll
                            for (int j = 0; j < 8; ++j) v[j] = s[(size_t)j * HWB];
                        }
                    }
                }
                uint4v hd, ld;
#pragma unroll
                for (int j = 0; j < 4; ++j) {
                    hd[j] = (v[2 * j] & 0xFFFFu) | (v[2 * j + 1] << 16);
                    ld[j] = (v[2 * j] >> 16) | (v[2 * j + 1] & 0xFFFF0000u);
                }
                *(uint4v*)&BH[(g * HALO + t) * 4] = hd;
                *(uint4v*)&BL[(g * HALO + t) * 4] = ld;
            }
        }
        __syncthreads();

        size_t wb = ((size_t)kb * COB + (coB >> 4) + wm * 2) * 512 + lane * 8;
        short8 ah0 = *(const short8*)(Whi + wb);
        short8 ah1 = *(const short8*)(Whi + wb + 512);
        short8 al0 = *(const short8*)(Wlo + wb);
        short8 al1 = *(const short8*)(Wlo + wb + 512);

        const int g = lane >> 4;
        const int pl = lane & 15;
        int dh = 0, dw = 0;
#pragma unroll 1
        for (int tap = 0; tap < 9; ++tap) {
            const size_t wbn = wb + ((tap < 8) ? wstride : 0);
            short8 nh0 = *(const short8*)(Whi + wbn);
            short8 nh1 = *(const short8*)(Whi + wbn + 512);
            short8 nl0 = *(const short8*)(Wlo + wbn);
            short8 nl1 = *(const short8*)(Wlo + wbn + 512);

#pragma unroll
            for (int fn = 0; fn < NFW; ++fn) {
                int pxf = (wn * NFW + fn) * 16 + pl;
                pxf = pxf < NPIX ? pxf : NPIX - 1;
                const int oy = pxf / TW, ox = pxf - oy * TW;
                const int hpx = (oy + dh) * HALO_W + (ox + dw);
                short8 bh = *(const short8*)&BH[(g * HALO + hpx) * 4];
                short8 bl = *(const short8*)&BL[(g * HALO + hpx) * 4];
                acc[0][fn] = mfma16(ah0, bh, acc[0][fn]);
                acc[1][fn] = mfma16(ah1, bh, acc[1][fn]);
                acc[0][fn] = mfma16(al0, bh, acc[0][fn]);
                acc[1][fn] = mfma16(al1, bh, acc[1][fn]);
                acc[0][fn] = mfma16(ah0, bl, acc[0][fn]);
                acc[1][fn] = mfma16(ah1, bl, acc[1][fn]);
            }
            ah0 = nh0; ah1 = nh1; al0 = nl0; al1 = nl1;
            wb = wbn;
            if (++dw == 3) { dw = 0; ++dh; }
        }
        __syncthreads();
    }

    const float* mcb = mc + (size_t)img * HWB;
#pragma unroll
    for (int fm = 0; fm < 2; ++fm)
#pragma unroll
    for (int fn = 0; fn < NFW; ++fn) {
        const int co = coB + (wm * 2 + fm) * 16 + (lane >> 4) * 4;
        const int pxf = (wn * NFW + fn) * 16 + (lane & 15);
        if (pxf >= NPIX) continue;
        const int oy = pxf / TW, ox = pxf - oy * TW;
        const int gy = oy0 + oy, gx = ox0 + ox;
        if (gy >= Hout || gx >= Wout) continue;
        const float m = mcb[(size_t)gy * Wout + gx];
        f32x4 a = acc[fm][fn];
#pragma unroll
        for (int r = 0; r < 4; ++r) {
            float y = a[r];
            if (EPI == EPI_F32_BIAS) {
                const float bv = bias[co + r];
                y = (m == 0.f) ? 0.f : (y - bv) / m + bv;
            } else {
                y = (m == 0.f) ? 0.f : y / m;
            }
            ((float*)outp)[((size_t)img * Cout + co + r) * HWB + (size_t)gy * Wout + gx] = y;
        }
    }
}

// ---------------------------------------------------------------------------
// BatchNorm (training-mode, biased var over N,H,W)
// ---------------------------------------------------------------------------
__global__ __launch_bounds__(256) void bn_stats_kernel(const float* __restrict__ y,
                                                       int N, int C, int HW,
                                                       float* __restrict__ mean,
                                                       float* __restrict__ istd) {
    const int c = blockIdx.x;
    double s = 0.0, s2 = 0.0;
    const int tot = N * HW;
    for (int i = threadIdx.x; i < tot; i += blockDim.x) {
        int n = i / HW, hw = i - n * HW;
        float v = y[((size_t)n * C + c) * HW + hw];
        s += v;
        s2 += (double)v * v;
    }
    __shared__ double sh[256], sh2[256];
    sh[threadIdx.x] = s; sh2[threadIdx.x] = s2;
    __syncthreads();
    for (int o = 128; o > 0; o >>= 1) {
        if (threadIdx.x < o) { sh[threadIdx.x] += sh[threadIdx.x + o]; sh2[threadIdx.x] += sh2[threadIdx.x + o]; }
        __syncthreads();
    }
    if (threadIdx.x == 0) {
        double mu = sh[0] / tot;
        double var = sh2[0] / tot - mu * mu;
        mean[c] = (float)mu;
        istd[c] = (float)(1.0 / sqrt(var + 1e-5));
    }
}

// BN apply + act; writes packed bf16-pair (and optional f32 copy)
__global__ void bn_apply_pair(const float* __restrict__ y,
                              const float* __restrict__ mean, const float* __restrict__ istd,
                              const float* __restrict__ g, const float* __restrict__ b,
                              unsigned* __restrict__ pout, float* __restrict__ fout,
                              int C, int HW, int total, int act) {
    int idx = blockIdx.x * blockDim.x + threadIdx.x;
    if (idx >= total) return;
    int c = (idx / HW) % C;
    float v = (y[idx] - mean[c]) * istd[c] * g[c] + b[c];
    v = actf(v, act);
    pout[idx] = splitpack(v);
    if (fout) fout[idx] = v;
}

// ---------------------------------------------------------------------------
// NLM feature swapping at h2 (B=8, C=512, Npix=1296)
// ---------------------------------------------------------------------------
#define NLM_C 512
#define NLM_N 1296

__global__ void nlm_prep_kernel(const float* __restrict__ h2, float* __restrict__ xT,
                                int Bn, int C, int Npix) {
    size_t idx = (size_t)blockIdx.x * blockDim.x + threadIdx.x;
    size_t total = (size_t)Bn * Npix * C;
    if (idx >= total) return;
    int c = (int)(idx % C);
    size_t t = idx / C;
    int j = (int)(t % Npix);
    int b = (int)(t / Npix);
    xT[idx] = h2[((size_t)b * C + c) * Npix + j];
}

__global__ void nlm_sq_kernel(const float* __restrict__ xT, float* __restrict__ sq,
                              int BN, int C) {
    int idx = blockIdx.x * blockDim.x + threadIdx.x;
    if (idx >= BN) return;
    const float* r = xT + (size_t)idx * C;
    float s = 0.f;
    for (int c = 0; c < C; ++c) s = fmaf(r[c], r[c], s);
    sq[idx] = s;
}

__global__ __launch_bounds__(256) void nlm_kernel(
    const float* __restrict__ xT, const float* __restrict__ sq,
    const float* __restrict__ mask,
    unsigned* __restrict__ out,     // packed bf16-pair h2s, NCHW
    float inv_h2) {
    const int i = blockIdx.x;
    const int b = blockIdx.y;
    const int tid = threadIdx.x;
    if (mask[(size_t)b * NLM_N + i] > 0.5f) return;

    __shared__ float Drow[NLM_N];
    __shared__ float xi[NLM_C];
    __shared__ float red[256];

    const float* xib = xT + ((size_t)b * NLM_N + i) * NLM_C;
    for (int c = tid; c < NLM_C; c += 256) xi[c] = xib[c];
    __syncthreads();

    const float sqi = sq[(size_t)b * NLM_N + i];
    const float BIG = 3.4e38f;
    float lmin = BIG;
    for (int j = tid; j < NLM_N; j += 256) {
        float d = BIG;
        if (mask[(size_t)b * NLM_N + j] > 0.5f) {
            const float* xj = xT + ((size_t)b * NLM_N + j) * NLM_C;
            float dot = 0.f;
            for (int c = 0; c < NLM_C; ++c) dot = fmaf(xi[c], xj[c], dot);
            d = sqi + sq[(size_t)b * NLM_N + j] - 2.f * dot;
            d = d > 0.f ? d : 0.f;
            lmin = d < lmin ? d : lmin;
        }
        Drow[j] = d;
    }
    red[tid] = lmin;
    __syncthreads();
    for (int o = 128; o > 0; o >>= 1) {
        if (tid < o) red[tid] = fminf(red[tid], red[tid + o]);
        __syncthreads();
    }
    const float dmin = red[0];
    __syncthreads();

    float lsum = 0.f;
    for (int j = tid; j < NLM_N; j += 256) {
        float wv = 0.f;
        if (Drow[j] < 3.3e38f) wv = expf(-(Drow[j] - dmin) * inv_h2);
        Drow[j] = wv;
        lsum += wv;
    }
    red[tid] = lsum;
    __syncthreads();
    for (int o = 128; o > 0; o >>= 1) {
        if (tid < o) red[tid] += red[tid + o];
        __syncthreads();
    }
    const float invw = 1.f / red[0];
    __syncthreads();

    for (int c = tid; c < NLM_C; c += 256) {
        float a = 0.f;
        for (int j = 0; j < NLM_N; ++j)
            a = fmaf(Drow[j], xT[((size_t)b * NLM_N + j) * NLM_C + c], a);
        out[((size_t)b * NLM_C + c) * NLM_N + i] = splitpack(a * invw);
    }
}

// ---------------------------------------------------------------------------
// Driver
// ---------------------------------------------------------------------------
extern "C" void kernel_launch(void* const* d_in, const int* in_sizes, int n_in,
                              void* d_out, int out_size, void* d_ws, size_t ws_size,
                              hipStream_t stream) {
    const float* x0    = (const float*)d_in[0];
    const float* m0    = (const float*)d_in[1];
    const float* Wsrc[8] = {
        (const float*)d_in[2], (const float*)d_in[3], (const float*)d_in[4],
        (const float*)d_in[5], (const float*)d_in[6], (const float*)d_in[7],
        (const float*)d_in[8], (const float*)d_in[9]
    };
    const float* dec1b = (const float*)d_in[10];
    const float* enc2g = (const float*)d_in[11];
    const float* enc2b = (const float*)d_in[12];
    const float* enc3g = (const float*)d_in[13];
    const float* enc3b = (const float*)d_in[14];
    const float* enc4g = (const float*)d_in[15];
    const float* enc4b = (const float*)d_in[16];
    const float* dec4g = (const float*)d_in[17];
    const float* dec4b = (const float*)d_in[18];
    const float* dec3g = (const float*)d_in[19];
    const float* dec3b = (const float*)d_in[20];
    const float* dec2g = (const float*)d_in[21];
    const float* dec2b = (const float*)d_in[22];
    float* outp = (float*)d_out;

    const int N = 8;
    float* ws = (float*)d_ws;
    size_t off = 0;
    auto alloc = [&](size_t nf) {
        size_t o = off;
        off += ((nf + 63) / 64) * 64;
        return ws + o;
    };

    unsigned* h1pair  = (unsigned*)alloc(10616832);  // 8x256x72x72  (later d2pair)
    unsigned* h2spair = (unsigned*)alloc(5308416);   // 8x512x36x36  (later d3pair)
    unsigned* h3pair  = (unsigned*)alloc(1327104);   // 8x512x18x18
    unsigned* h4pair  = (unsigned*)alloc(331776);    // 8x512x9x9
    unsigned* d4pair  = (unsigned*)alloc(1327104);
    float* ybuf = alloc(10616832);                   // pre-BN f32 scratch (max dec2)
    float* h2f  = alloc(5308416);                    // f32 h2 for NLM
    float* xT   = alloc(5308416);
    float* sqb  = alloc(10368);
    float* mc   = alloc(165888);
    float* nm1  = alloc(41472);
    float* nm2  = alloc(10368);
    float* nm3  = alloc(2592);
    float* nm4  = alloc(648);
    float* nmd4 = alloc(2592);
    float* nmd3 = alloc(10368);
    float* nmd2 = alloc(41472);
    float* nmx  = alloc(165888);
    float* bmean = alloc(512);
    float* bistd = alloc(512);
    short* Whi = (short*)alloc(10625024);            // 21,250,048 bf16
    short* Wlo = (short*)alloc(10625024);
    unsigned* d3pair = h2spair;  // h2spair dead after dec3 conv
    unsigned* d2pair = h1pair;   // h1pair dead after dec2 conv

    if (ws_size < off * sizeof(float)) return;  // workspace too small; fail loudly

    auto cdiv = [](size_t a, size_t b) { return (int)((a + b - 1) / b); };

    // ---- weight transforms (A-fragment layout, bf16 hi/lo) ----
    struct WLay { int Cout, Cin, K; size_t ofs; };
    const WLay WL[8] = {
        {256, 128, 7, 0},         // enc1
        {512, 256, 5, 1605632},   // enc2
        {512, 512, 3, 4882432},   // enc3
        {512, 512, 3, 7241728},   // enc4
        {512, 1024, 3, 9601024},  // dec4
        {512, 1024, 3, 14319616}, // dec3
        {256, 768, 3, 19038208},  // dec2
        {128, 384, 3, 20807680},  // dec1
    };
    for (int i = 0; i < 8; ++i) {
        size_t tot = (size_t)WL[i].Cout * WL[i].Cin * WL[i].K * WL[i].K;
        wtransform<<<cdiv(tot, 256), 256, 0, stream>>>(
            Wsrc[i], Whi + WL[i].ofs, Wlo + WL[i].ofs, WL[i].Cout, WL[i].Cin,
            WL[i].K * WL[i].K, tot);
    }

    // ---------------- enc1: 128->256, 7x7 s2 p3, relu, no BN ----------------
    maskconv_kernel<7, 2, false><<<cdiv(N * 72 * 72, 256), 256, 0, stream>>>(
        m0, 144, 144, mc, nm1, N, 144, 144, 72, 72);
    conv_enc<7, 2, 8, 8, 2, true, EPI_PAIR_RELU><<<dim3(81, 1, N), 512, 0, stream>>>(
        x0, 128, 144, 144, m0,
        Whi + WL[0].ofs, Wlo + WL[0].ofs, mc, nullptr, h1pair,
        72, 72, 256, 9);

    // ---------------- enc2: 256->512, 5x5 s2 p2, BN+relu ----------------
    maskconv_kernel<5, 2, false><<<cdiv(N * 36 * 36, 256), 256, 0, stream>>>(
        nm1, 72, 72, mc, nm2, N, 72, 72, 36, 36);
    conv_enc<5, 2, 8, 8, 2, false, EPI_F32><<<dim3(25, 2, N), 512, 0, stream>>>(
        h1pair, 256, 72, 72, nm1,
        Whi + WL[1].ofs, Wlo + WL[1].ofs, mc, nullptr, ybuf,
        36, 36, 512, 5);
    bn_stats_kernel<<<512, 256, 0, stream>>>(ybuf, N, 512, 1296, bmean, bistd);
    bn_apply_pair<<<cdiv(5308416, 256), 256, 0, stream>>>(
        ybuf, bmean, bistd, enc2g, enc2b, h2spair, h2f, 512, 1296, 5308416, ACT_RELU);

    // ---------------- NLM swap at h2 ----------------
    nlm_prep_kernel<<<cdiv(5308416, 256), 256, 0, stream>>>(h2f, xT, N, 512, 1296);
    nlm_sq_kernel<<<cdiv(N * 1296, 256), 256, 0, stream>>>(xT, sqb, N * 1296, 512);
    nlm_kernel<<<dim3(1296, N), 256, 0, stream>>>(xT, sqb, nm2, h2spair, 1.f / 25.f);

    // ---------------- enc3: 512->512, 3x3 s2 p1, BN+relu ----------------
    maskconv_kernel<3, 2, false><<<cdiv(N * 18 * 18, 256), 256, 0, stream>>>(
        nm2, 36, 36, mc, nm3, N, 36, 36, 18, 18);
    conv_enc<3, 2, 4, 8, 1, false, EPI_F32><<<dim3(15, 2, N), 512, 0, stream>>>(
        h2spair, 512, 36, 36, nm2,
        Whi + WL[2].ofs, Wlo + WL[2].ofs, mc, nullptr, ybuf,
        18, 18, 512, 3);
    bn_stats_kernel<<<512, 256, 0, stream>>>(ybuf, N, 512, 324, bmean, bistd);
    bn_apply_pair<<<cdiv(1327104, 256), 256, 0, stream>>>(
        ybuf, bmean, bistd, enc3g, enc3b, h3pair, nullptr, 512, 324, 1327104, ACT_RELU);

    // ---------------- enc4: 512->512, 3x3 s2 p1, BN+relu ----------------
    maskconv_kernel<3, 2, false><<<cdiv(N * 9 * 9, 256), 256, 0, stream>>>(
        nm3, 18, 18, mc, nm4, N, 18, 18, 9, 9);
    conv_enc<3, 2, 4, 8, 1, false, EPI_F32><<<dim3(6, 2, N), 512, 0, stream>>>(
        h3pair, 512, 18, 18, nm3,
        Whi + WL[3].ofs, Wlo + WL[3].ofs, mc, nullptr, ybuf,
        9, 9, 512, 2);
    bn_stats_kernel<<<512, 256, 0, stream>>>(ybuf, N, 512, 81, bmean, bistd);
    bn_apply_pair<<<cdiv(331776, 256), 256, 0, stream>>>(
        ybuf, bmean, bistd, enc4g, enc4b, h4pair, nullptr, 512, 81, 331776, ACT_RELU);

    // ---------------- dec4: cat[up2(h4), h3] 1024->512 @18, BN+leaky ----------------
    maskconv_kernel<3, 1, true><<<cdiv(N * 18 * 18, 256), 256, 0, stream>>>(
        nm4, 9, 9, mc, nmd4, N, 18, 18, 18, 18);
    conv3x3<9, 6, 4, false, EPI_F32><<<dim3(6, 4, N), 512, 0, stream>>>(
        h4pair, 512, 9, 9, h3pair, 512, nm4,
        Whi + WL[4].ofs, Wlo + WL[4].ofs, mc, nullptr, ybuf,
        18, 18, 512, 3);
    bn_stats_kernel<<<512, 256, 0, stream>>>(ybuf, N, 512, 324, bmean, bistd);
    bn_apply_pair<<<cdiv(1327104, 256), 256, 0, stream>>>(
        ybuf, bmean, bistd, dec4g, dec4b, d4pair, nullptr, 512, 324, 1327104, ACT_LEAKY);

    // ---------------- dec3: cat[up2(d4), h2s] 1024->512 @36, BN+leaky ----------------
    maskconv_kernel<3, 1, true><<<cdiv(N * 36 * 36, 256), 256, 0, stream>>>(
        nmd4, 18, 18, mc, nmd3, N, 36, 36, 36, 36);
    conv3x3<12, 8, 6, false, EPI_F32><<<dim3(15, 4, N), 512, 0, stream>>>(
        d4pair, 512, 18, 18, h2spair, 512, nmd4,
        Whi + WL[5].ofs, Wlo + WL[5].ofs, mc, nullptr, ybuf,
        36, 36, 512, 5);
    bn_stats_kernel<<<512, 256, 0, stream>>>(ybuf, N, 512, 1296, bmean, bistd);
    bn_apply_pair<<<cdiv(5308416, 256), 256, 0, stream>>>(
        ybuf, bmean, bistd, dec3g, dec3b, d3pair, nullptr, 512, 1296, 5308416, ACT_LEAKY);

    // ---------------- dec2: cat[up2(d3), h1] 768->256 @72, BN+leaky ----------------
    maskconv_kernel<3, 1, true><<<cdiv(N * 72 * 72, 256), 256, 0, stream>>>(
        nmd3, 36, 36, mc, nmd2, N, 72, 72, 72, 72);
    conv3x3<8, 12, 6, false, EPI_F32><<<dim3(54, 2, N), 512, 0, stream>>>(
        d3pair, 512, 36, 36, h1pair, 256, nmd3,
        Whi + WL[6].ofs, Wlo + WL[6].ofs, mc, nullptr, ybuf,
        72, 72, 256, 6);
    bn_stats_kernel<<<256, 256, 0, stream>>>(ybuf, N, 256, 5184, bmean, bistd);
    bn_apply_pair<<<cdiv(10616832, 256), 256, 0, stream>>>(
        ybuf, bmean, bistd, dec2g, dec2b, d2pair, nullptr, 256, 5184, 10616832, ACT_LEAKY);

    // ---------------- dec1: cat[up2(d2), x0] 384->128 @144, bias, no BN/act ----------------
    maskconv_kernel<3, 1, true><<<cdiv(N * 144 * 144, 256), 256, 0, stream>>>(
        nmd2, 72, 72, mc, nmx, N, 144, 144, 144, 144);
    conv3x3<16, 16, 16, true, EPI_F32_BIAS><<<dim3(81, 1, N), 512, 0, stream>>>(
        d2pair, 256, 72, 72, x0, 128, nmd2,
        Whi + WL[7].ofs, Wlo + WL[7].ofs, mc, dec1b, outp,
        144, 144, 128, 9);
}

// Round 5
// 2836.225 us; speedup vs baseline: 108.1491x; 1.2395x over previous
//
#include <hip/hip_runtime.h>
#include <math.h>

#define ACT_NONE 0
#define ACT_RELU 1
#define ACT_LEAKY 2

#define EPI_F32 0
#define EPI_PAIR_RELU 1
#define EPI_F32_BIAS 2

typedef __attribute__((ext_vector_type(8))) short short8;
typedef __attribute__((ext_vector_type(8))) __bf16 bf16x8;
typedef __attribute__((ext_vector_type(4))) float f32x4;
typedef __attribute__((ext_vector_type(4))) unsigned uint4v;

__device__ __forceinline__ float actf(float y, int act) {
    if (act == ACT_RELU)  return y > 0.f ? y : 0.f;
    if (act == ACT_LEAKY) return y >= 0.f ? y : 0.2f * y;
    return y;
}

// ---- bf16 split helpers: f32 -> (hi,lo) bf16 pair packed in u32 (hi in low 16) ----
__device__ __forceinline__ unsigned f2bf_rne(float f) {
    unsigned u = __float_as_uint(f);
    return (u + 0x7FFFu + ((u >> 16) & 1u)) >> 16;
}
__device__ __forceinline__ float bf2f(unsigned h) { return __uint_as_float(h << 16); }
__device__ __forceinline__ unsigned splitpack(float f) {
    unsigned hi = f2bf_rne(f);
    float r = f - bf2f(hi);
    unsigned lo = f2bf_rne(r);
    return (hi & 0xFFFFu) | (lo << 16);
}

__device__ __forceinline__ f32x4 mfma16(short8 a, short8 b, f32x4 c) {
    return __builtin_amdgcn_mfma_f32_16x16x32_bf16(
        __builtin_bit_cast(bf16x8, a), __builtin_bit_cast(bf16x8, b), c, 0, 0, 0);
}

// ---------------------------------------------------------------------------
// Mask convolution: mc = conv(mask, ones(K,K), stride S, pad P); nm = (mc!=0)
// ---------------------------------------------------------------------------
template<int K, int S, bool MHALF>
__global__ void maskconv_kernel(const float* __restrict__ M, int HM, int WM,
                                float* __restrict__ mc, float* __restrict__ nm,
                                int N, int Hin, int Win, int Hout, int Wout) {
    constexpr int P = (K - 1) / 2;
    int idx = blockIdx.x * blockDim.x + threadIdx.x;
    int total = N * Hout * Wout;
    if (idx >= total) return;
    int wo = idx % Wout;
    int t  = idx / Wout;
    int ho = t % Hout;
    int n  = t / Hout;
    float s = 0.f;
    for (int kh = 0; kh < K; ++kh) {
        int ih = ho * S - P + kh;
        if ((unsigned)ih >= (unsigned)Hin) continue;
        const float* mrow = M + ((size_t)n * HM + (MHALF ? (ih >> 1) : ih)) * WM;
        for (int kw = 0; kw < K; ++kw) {
            int iw = wo * S - P + kw;
            if ((unsigned)iw < (unsigned)Win)
                s += mrow[MHALF ? (iw >> 1) : iw];
        }
    }
    mc[idx] = s;
    nm[idx] = (s == 0.f) ? 0.f : 1.f;
}

// ---------------------------------------------------------------------------
// Weight transform: W[co][ci][kh][kw] f32 -> A-fragment layout bf16 hi/lo
// ---------------------------------------------------------------------------
__global__ void wtransform(const float* __restrict__ W, short* __restrict__ Whi,
                           short* __restrict__ Wlo, int Cout, int Cin, int Ksz,
                           size_t total) {
    size_t idx = (size_t)blockIdx.x * blockDim.x + threadIdx.x;
    if (idx >= total) return;
    int j = (int)(idx & 7);
    int lane = (int)((idx >> 3) & 63);
    size_t r = idx >> 9;
    int COB = Cout >> 4, KB = Cin >> 5;
    int cob = (int)(r % COB); r /= COB;
    int kb = (int)(r % KB);
    int tap = (int)(r / KB);
    int co = cob * 16 + (lane & 15);
    int ci = kb * 32 + (lane >> 4) * 8 + j;
    float f = W[((size_t)co * Cin + ci) * Ksz + tap];
    unsigned hi = f2bf_rne(f);
    float rr = f - bf2f(hi);
    unsigned lo = f2bf_rne(rr);
    Whi[idx] = (short)hi;
    Wlo[idx] = (short)lo;
}

// ---------------------------------------------------------------------------
// Encoder halo-staged stride-S conv (full K*K tap reuse from LDS).
// ---------------------------------------------------------------------------
template<int K, int S, int TH, int TW, int NFW, bool AF32, int EPI>
__global__ __launch_bounds__(512) void conv_enc(
    const void* __restrict__ Asrc, int Cin, int Hin, int Win,
    const float* __restrict__ M,
    const short* __restrict__ Whi, const short* __restrict__ Wlo,
    const float* __restrict__ mc, const float* __restrict__ bias,
    void* __restrict__ outp,
    int Hout, int Wout, int Cout, int TX)
{
    constexpr int P = (K - 1) / 2;
    constexpr int HH  = (TH - 1) * S + K;
    constexpr int HWC = (TW - 1) * S + K;
    constexpr int PXC = HH * HWC;
    __shared__ __align__(16) unsigned BH[4 * PXC * 4];
    __shared__ __align__(16) unsigned BL[4 * PXC * 4];

    const int t    = threadIdx.x;
    const int lane = t & 63;
    const int wv   = t >> 6;
    const int wm   = wv >> 1;
    const int wn   = wv & 1;
    const int img  = blockIdx.z;
    const int coB  = blockIdx.y * 256;
    const int tile = blockIdx.x;
    const int ty   = tile / TX, tx = tile - ty * TX;
    const int oy0  = ty * TH, ox0 = tx * TW;
    const int KB   = Cin >> 5;
    const int COB  = Cout >> 4;
    const size_t HW = (size_t)Hin * Win;
    const int g  = lane >> 4;
    const int pl = lane & 15;

    f32x4 acc[4][NFW] = {};

#pragma unroll 1
    for (int kb = 0; kb < KB; ++kb) {
        for (int q = t; q < PXC; q += 512) {
            const int r = q / HWC, c = q - r * HWC;
            const int iy = oy0 * S - P + r;
            const int ix = ox0 * S - P + c;
            bool sel = (unsigned)iy < (unsigned)Hin && (unsigned)ix < (unsigned)Win;
            size_t base = 0;
            if (sel) {
                sel = M[(size_t)img * HW + (size_t)iy * Win + ix] != 0.f;
                base = (size_t)img * Cin * HW + (size_t)iy * Win + ix;
            }
#pragma unroll
            for (int gg = 0; gg < 4; ++gg) {
                const int c0 = kb * 32 + gg * 8;
                unsigned v[8];
#pragma unroll
                for (int j = 0; j < 8; ++j) v[j] = 0u;
                if (sel) {
                    if (AF32) {
                        const float* s = (const float*)Asrc + base + (size_t)c0 * HW;
#pragma unroll
                        for (int j = 0; j < 8; ++j) v[j] = splitpack(s[(size_t)j * HW]);
                    } else {
                        const unsigned* s = (const unsigned*)Asrc + base + (size_t)c0 * HW;
#pragma unroll
                        for (int j = 0; j < 8; ++j) v[j] = s[(size_t)j * HW];
                    }
                }
                uint4v hd, ld;
#pragma unroll
                for (int j = 0; j < 4; ++j) {
                    hd[j] = (v[2 * j] & 0xFFFFu) | (v[2 * j + 1] << 16);
                    ld[j] = (v[2 * j] >> 16) | (v[2 * j + 1] & 0xFFFF0000u);
                }
                *(uint4v*)&BH[(gg * PXC + q) * 4] = hd;
                *(uint4v*)&BL[(gg * PXC + q) * 4] = ld;
            }
        }
        __syncthreads();

#pragma unroll 1
        for (int kh = 0; kh < K; ++kh)
#pragma unroll 1
        for (int kw = 0; kw < K; ++kw) {
            const int tap = kh * K + kw;
            const size_t wb = (((size_t)tap * KB + kb) * COB + (coB >> 4) + wm * 4) * 512
                            + (size_t)lane * 8;
            short8 ah[4], al[4];
#pragma unroll
            for (int fm = 0; fm < 4; ++fm) {
                ah[fm] = *(const short8*)(Whi + wb + (size_t)fm * 512);
                al[fm] = *(const short8*)(Wlo + wb + (size_t)fm * 512);
            }
#pragma unroll
            for (int fn = 0; fn < NFW; ++fn) {
                const int pxf = (wn * NFW + fn) * 16 + pl;
                const int oy = pxf / TW, ox = pxf - oy * TW;
                const int h = (oy * S + kh) * HWC + ox * S + kw;
                short8 bh = *(const short8*)&BH[(g * PXC + h) * 4];
                short8 bl = *(const short8*)&BL[(g * PXC + h) * 4];
#pragma unroll
                for (int fm = 0; fm < 4; ++fm) {
                    acc[fm][fn] = mfma16(ah[fm], bh, acc[fm][fn]);
                    acc[fm][fn] = mfma16(al[fm], bh, acc[fm][fn]);
                    acc[fm][fn] = mfma16(ah[fm], bl, acc[fm][fn]);
                }
            }
        }
        __syncthreads();
    }

    const int Npix = Hout * Wout;
    const float* mcb = mc + (size_t)img * Npix;
#pragma unroll
    for (int fm = 0; fm < 4; ++fm)
#pragma unroll
    for (int fn = 0; fn < NFW; ++fn) {
        const int co = coB + (wm * 4 + fm) * 16 + (lane >> 4) * 4;
        const int pxf = (wn * NFW + fn) * 16 + (lane & 15);
        const int oy = pxf / TW, ox = pxf - oy * TW;
        const int gy = oy0 + oy, gx = ox0 + ox;
        if (gy >= Hout || gx >= Wout) continue;
        const float m = mcb[(size_t)gy * Wout + gx];
        f32x4 a = acc[fm][fn];
#pragma unroll
        for (int r = 0; r < 4; ++r) {
            float y = a[r];
            if (EPI == EPI_F32_BIAS) {
                const float bv = bias[co + r];
                y = (m == 0.f) ? 0.f : (y - bv) / m + bv;
            } else {
                y = (m == 0.f) ? 0.f : y / m;
            }
            const size_t oidx = ((size_t)img * Cout + co + r) * Npix + (size_t)gy * Wout + gx;
            if (EPI == EPI_PAIR_RELU) {
                y = y > 0.f ? y : 0.f;
                ((unsigned*)outp)[oidx] = splitpack(y);
            } else {
                ((float*)outp)[oidx] = y;
            }
        }
    }
}

// ---------------------------------------------------------------------------
// Decoder halo-staged 3x3 s1 p1 partial conv.
// ---------------------------------------------------------------------------
template<int TH, int TW, int NF, bool BF32, int EPI>
__global__ __launch_bounds__(512) void conv3x3(
    const void* __restrict__ Asrc, int CA, int HA, int WA,
    const void* __restrict__ Bsrc, int CB,
    const float* __restrict__ M,
    const short* __restrict__ Whi, const short* __restrict__ Wlo,
    const float* __restrict__ mc, const float* __restrict__ bias,
    void* __restrict__ outp,
    int Hout, int Wout, int Cout, int TX)
{
    constexpr int HALO_H = TH + 2, HALO_W = TW + 2, HALO = HALO_H * HALO_W;
    constexpr int NFW = NF / 2;
    constexpr int NPIX = TH * TW;
    __shared__ __align__(16) unsigned BH[4 * HALO * 4];
    __shared__ __align__(16) unsigned BL[4 * HALO * 4];

    const int t    = threadIdx.x;
    const int lane = t & 63;
    const int wv   = t >> 6;
    const int wm   = wv >> 1;
    const int wn   = wv & 1;
    const int img  = blockIdx.z;
    const int coB  = blockIdx.y * 128;
    const int tile = blockIdx.x;
    const int ty   = tile / TX;
    const int tx   = tile - ty * TX;
    const int oy0  = ty * TH, ox0 = tx * TW;
    const int Cin  = CA + CB;
    const int KB   = Cin >> 5;
    const int COB  = Cout >> 4;
    const int WM   = Wout >> 1;
    const size_t HWA = (size_t)HA * WA;
    const size_t HWB = (size_t)Hout * Wout;

    bool sel = false;
    size_t abase = 0, bbase = 0;
    if (t < HALO) {
        const int hy = t / HALO_W, hx = t - hy * HALO_W;
        const int iy = oy0 - 1 + hy, ix = ox0 - 1 + hx;
        if ((unsigned)iy < (unsigned)Hout && (unsigned)ix < (unsigned)Wout) {
            sel = M[((size_t)img * (Hout >> 1) + (iy >> 1)) * WM + (ix >> 1)] != 0.f;
            if (sel) {
                abase = (size_t)img * CA * HWA + (size_t)(iy >> 1) * WA + (ix >> 1);
                bbase = (size_t)img * CB * HWB + (size_t)iy * Wout + ix;
            }
        }
    }

    f32x4 acc[2][NFW] = {};
    const size_t wstride = (size_t)KB * COB * 512;

#pragma unroll 1
    for (int kb = 0; kb < KB; ++kb) {
        if (t < HALO) {
            const int ci0 = kb * 32;
#pragma unroll
            for (int g = 0; g < 4; ++g) {
                const int c = ci0 + g * 8;
                unsigned v[8];
#pragma unroll
                for (int j = 0; j < 8; ++j) v[j] = 0u;
                if (sel) {
                    if (c < CA) {
                        const unsigned* s = (const unsigned*)Asrc + abase + (size_t)c * HWA;
#pragma unroll
                        for (int j = 0; j < 8; ++j) v[j] = s[(size_t)j * HWA];
                    } else {
                        if (BF32) {
                            const float* s = (const float*)Bsrc + bbase + (size_t)(c - CA) * HWB;
#pragma unroll
                            for (int j = 0; j < 8; ++j) v[j] = splitpack(s[(size_t)j * HWB]);
                        } else {
                            const unsigned* s = (const unsigned*)Bsrc + bbase + (size_t)(c - CA) * HWB;
#pragma unroll
                            for (int j = 0; j < 8; ++j) v[j] = s[(size_t)j * HWB];
                        }
                    }
                }
                uint4v hd, ld;
#pragma unroll
                for (int j = 0; j < 4; ++j) {
                    hd[j] = (v[2 * j] & 0xFFFFu) | (v[2 * j + 1] << 16);
                    ld[j] = (v[2 * j] >> 16) | (v[2 * j + 1] & 0xFFFF0000u);
                }
                *(uint4v*)&BH[(g * HALO + t) * 4] = hd;
                *(uint4v*)&BL[(g * HALO + t) * 4] = ld;
            }
        }
        __syncthreads();

        size_t wb = ((size_t)kb * COB + (coB >> 4) + wm * 2) * 512 + lane * 8;
        short8 ah0 = *(const short8*)(Whi + wb);
        short8 ah1 = *(const short8*)(Whi + wb + 512);
        short8 al0 = *(const short8*)(Wlo + wb);
        short8 al1 = *(const short8*)(Wlo + wb + 512);

        const int g = lane >> 4;
        const int pl = lane & 15;
        int dh = 0, dw = 0;
#pragma unroll 1
        for (int tap = 0; tap < 9; ++tap) {
            const size_t wbn = wb + ((tap < 8) ? wstride : 0);
            short8 nh0 = *(const short8*)(Whi + wbn);
            short8 nh1 = *(const short8*)(Whi + wbn + 512);
            short8 nl0 = *(const short8*)(Wlo + wbn);
            short8 nl1 = *(const short8*)(Wlo + wbn + 512);

#pragma unroll
            for (int fn = 0; fn < NFW; ++fn) {
                int pxf = (wn * NFW + fn) * 16 + pl;
                pxf = pxf < NPIX ? pxf : NPIX - 1;
                const int oy = pxf / TW, ox = pxf - oy * TW;
                const int hpx = (oy + dh) * HALO_W + (ox + dw);
                short8 bh = *(const short8*)&BH[(g * HALO + hpx) * 4];
                short8 bl = *(const short8*)&BL[(g * HALO + hpx) * 4];
                acc[0][fn] = mfma16(ah0, bh, acc[0][fn]);
                acc[1][fn] = mfma16(ah1, bh, acc[1][fn]);
                acc[0][fn] = mfma16(al0, bh, acc[0][fn]);
                acc[1][fn] = mfma16(al1, bh, acc[1][fn]);
                acc[0][fn] = mfma16(ah0, bl, acc[0][fn]);
                acc[1][fn] = mfma16(ah1, bl, acc[1][fn]);
            }
            ah0 = nh0; ah1 = nh1; al0 = nl0; al1 = nl1;
            wb = wbn;
            if (++dw == 3) { dw = 0; ++dh; }
        }
        __syncthreads();
    }

    const float* mcb = mc + (size_t)img * HWB;
#pragma unroll
    for (int fm = 0; fm < 2; ++fm)
#pragma unroll
    for (int fn = 0; fn < NFW; ++fn) {
        const int co = coB + (wm * 2 + fm) * 16 + (lane >> 4) * 4;
        const int pxf = (wn * NFW + fn) * 16 + (lane & 15);
        if (pxf >= NPIX) continue;
        const int oy = pxf / TW, ox = pxf - oy * TW;
        const int gy = oy0 + oy, gx = ox0 + ox;
        if (gy >= Hout || gx >= Wout) continue;
        const float m = mcb[(size_t)gy * Wout + gx];
        f32x4 a = acc[fm][fn];
#pragma unroll
        for (int r = 0; r < 4; ++r) {
            float y = a[r];
            if (EPI == EPI_F32_BIAS) {
                const float bv = bias[co + r];
                y = (m == 0.f) ? 0.f : (y - bv) / m + bv;
            } else {
                y = (m == 0.f) ? 0.f : y / m;
            }
            ((float*)outp)[((size_t)img * Cout + co + r) * HWB + (size_t)gy * Wout + gx] = y;
        }
    }
}

// ---------------------------------------------------------------------------
// BatchNorm (training-mode, biased var over N,H,W)
// ---------------------------------------------------------------------------
__global__ __launch_bounds__(256) void bn_stats_kernel(const float* __restrict__ y,
                                                       int N, int C, int HW,
                                                       float* __restrict__ mean,
                                                       float* __restrict__ istd) {
    const int c = blockIdx.x;
    double s = 0.0, s2 = 0.0;
    const int tot = N * HW;
    for (int i = threadIdx.x; i < tot; i += blockDim.x) {
        int n = i / HW, hw = i - n * HW;
        float v = y[((size_t)n * C + c) * HW + hw];
        s += v;
        s2 += (double)v * v;
    }
    __shared__ double sh[256], sh2[256];
    sh[threadIdx.x] = s; sh2[threadIdx.x] = s2;
    __syncthreads();
    for (int o = 128; o > 0; o >>= 1) {
        if (threadIdx.x < o) { sh[threadIdx.x] += sh[threadIdx.x + o]; sh2[threadIdx.x] += sh2[threadIdx.x + o]; }
        __syncthreads();
    }
    if (threadIdx.x == 0) {
        double mu = sh[0] / tot;
        double var = sh2[0] / tot - mu * mu;
        mean[c] = (float)mu;
        istd[c] = (float)(1.0 / sqrt(var + 1e-5));
    }
}

__global__ void bn_apply_pair(const float* __restrict__ y,
                              const float* __restrict__ mean, const float* __restrict__ istd,
                              const float* __restrict__ g, const float* __restrict__ b,
                              unsigned* __restrict__ pout, float* __restrict__ fout,
                              int C, int HW, int total, int act) {
    int idx = blockIdx.x * blockDim.x + threadIdx.x;
    if (idx >= total) return;
    int c = (idx / HW) % C;
    float v = (y[idx] - mean[c]) * istd[c] * g[c] + b[c];
    v = actf(v, act);
    pout[idx] = splitpack(v);
    if (fout) fout[idx] = v;
}

// ---------------------------------------------------------------------------
// NLM feature swapping at h2 -- MFMA formulation.
//   B=8, C=512, Npix=1296, miss rows capped at NLM_MAXM.
// ---------------------------------------------------------------------------
#define NLM_C 512
#define NLM_N 1296
#define NLM_MAXM 256
#define NLM_RT 16            // NLM_MAXM/16 row-tiles
#define NLM_KB1 16           // 512/32
#define NLM_KB2 41           // ceil(1296/32) -> K padded to 1312
#define NLM_PFRAG (NLM_KB1 * NLM_RT * 512)   // shorts per image (Phi/Plo)
#define NLM_WFRAG (NLM_KB2 * NLM_RT * 512)   // shorts per image (W2hi/W2lo)

// h2f [b][c][j] -> xTp [b][j][c] packed bf16-pair, via 32x32 LDS tile
__global__ __launch_bounds__(256) void nlm_trans(const float* __restrict__ h2f,
                                                 unsigned* __restrict__ xTp) {
    __shared__ float tile[32][33];
    const int b = blockIdx.z;
    const int j0 = blockIdx.x * 32, c0 = blockIdx.y * 32;
    const int tx = threadIdx.x & 31, ty = threadIdx.x >> 5;
    for (int cc = ty; cc < 32; cc += 8) {
        const int j = j0 + tx;
        tile[cc][tx] = (j < NLM_N) ? h2f[((size_t)b * NLM_C + c0 + cc) * NLM_N + j] : 0.f;
    }
    __syncthreads();
    for (int jj = ty; jj < 32; jj += 8) {
        const int j = j0 + jj;
        if (j < NLM_N)
            xTp[((size_t)b * NLM_N + j) * NLM_C + c0 + tx] = splitpack(tile[tx][jj]);
    }
}

// sq[b][j] = sum_c h2f[b][c][j]^2  (coalesced over j)
__global__ void nlm_sq2(const float* __restrict__ h2f, float* __restrict__ sq) {
    const int b = blockIdx.y;
    const int j = blockIdx.x * 256 + threadIdx.x;
    if (j >= NLM_N) return;
    const float* p = h2f + (size_t)b * NLM_C * NLM_N + j;
    float s0 = 0.f, s1 = 0.f, s2 = 0.f, s3 = 0.f;
    for (int c = 0; c < NLM_C; c += 4) {
        float v0 = p[(size_t)c * NLM_N];
        float v1 = p[(size_t)(c + 1) * NLM_N];
        float v2 = p[(size_t)(c + 2) * NLM_N];
        float v3 = p[(size_t)(c + 3) * NLM_N];
        s0 = fmaf(v0, v0, s0); s1 = fmaf(v1, v1, s1);
        s2 = fmaf(v2, v2, s2); s3 = fmaf(v3, v3, s3);
    }
    sq[b * NLM_N + j] = (s0 + s1) + (s2 + s3);
}

// miss-pixel compaction (list order nondeterministic; outputs row-local -> ok)
__global__ void nlm_compact(const float* __restrict__ nm2, int* __restrict__ list,
                            int* __restrict__ cnt) {
    const int b = blockIdx.x;
    for (int j = threadIdx.x; j < NLM_N; j += 256) {
        if (nm2[(size_t)b * NLM_N + j] == 0.f) {
            int pos = atomicAdd(&cnt[b], 1);
            if (pos < NLM_MAXM) list[b * NLM_MAXM + pos] = j;
        }
    }
}

// gather miss rows of xTp into A-fragment layout (Phi/Plo); zero pad rows
__global__ void nlm_gather(const unsigned* __restrict__ xTp, const int* __restrict__ list,
                           const int* __restrict__ cnt,
                           short* __restrict__ Phi, short* __restrict__ Plo) {
    const int b = blockIdx.y;
    const int id = blockIdx.x * 256 + threadIdx.x;   // 16384 per image
    const int i  = id >> 6;            // row 0..255
    const int rem = id & 63;
    const int kb = rem >> 2, kg = rem & 3;
    const int lane = kg * 16 + (i & 15), rt = i >> 4;
    const size_t f = (size_t)b * NLM_PFRAG + ((size_t)(kb * NLM_RT + rt) * 64 + lane) * 8;
    if (i < cnt[b]) {
        const int pix = list[b * NLM_MAXM + i];
        const unsigned* s = xTp + ((size_t)b * NLM_N + pix) * NLM_C + kb * 32 + kg * 8;
#pragma unroll
        for (int jj = 0; jj < 8; ++jj) {
            unsigned v = s[jj];
            Phi[f + jj] = (short)(v & 0xFFFFu);
            Plo[f + jj] = (short)(v >> 16);
        }
    } else {
#pragma unroll
        for (int jj = 0; jj < 8; ++jj) { Phi[f + jj] = 0; Plo[f + jj] = 0; }
    }
}

// GEMM1: S[i][j] = x_miss[i] . x[j]   (M<=256, N=1296, K=512)
__global__ __launch_bounds__(512) void nlm_gemm1(
    const unsigned* __restrict__ xTp, const short* __restrict__ Phi,
    const short* __restrict__ Plo, const int* __restrict__ cnt,
    float* __restrict__ S) {
    const int img = blockIdx.z, mt = blockIdx.y, nt = blockIdx.x;
    if (mt * 128 >= cnt[img]) return;
    __shared__ __align__(16) unsigned BH[4 * 128 * 4];
    __shared__ __align__(16) unsigned BL[4 * 128 * 4];
    const int t = threadIdx.x, lane = t & 63, wv = t >> 6, wm = wv >> 1, wn = wv & 1;
    const int j0 = nt * 128;
    const int spx = t & 127, sg = t >> 7;
    f32x4 acc[2][4] = {};
#pragma unroll 1
    for (int kb = 0; kb < NLM_KB1; ++kb) {
        unsigned v[8];
#pragma unroll
        for (int jj = 0; jj < 8; ++jj) v[jj] = 0u;
        const int j = j0 + spx;
        if (j < NLM_N) {
            const unsigned* s = xTp + ((size_t)img * NLM_N + j) * NLM_C + kb * 32 + sg * 8;
#pragma unroll
            for (int jj = 0; jj < 8; ++jj) v[jj] = s[jj];
        }
        uint4v hd, ld;
#pragma unroll
        for (int jj = 0; jj < 4; ++jj) {
            hd[jj] = (v[2 * jj] & 0xFFFFu) | (v[2 * jj + 1] << 16);
            ld[jj] = (v[2 * jj] >> 16) | (v[2 * jj + 1] & 0xFFFF0000u);
        }
        *(uint4v*)&BH[(sg * 128 + spx) * 4] = hd;
        *(uint4v*)&BL[(sg * 128 + spx) * 4] = ld;
        __syncthreads();
        const size_t ab = (size_t)img * NLM_PFRAG
                        + (size_t)(kb * NLM_RT + mt * 8 + wm * 2) * 512 + (size_t)lane * 8;
        short8 ah0 = *(const short8*)(Phi + ab);
        short8 ah1 = *(const short8*)(Phi + ab + 512);
        short8 al0 = *(const short8*)(Plo + ab);
        short8 al1 = *(const short8*)(Plo + ab + 512);
        const int g = lane >> 4, pl = lane & 15;
#pragma unroll
        for (int fn = 0; fn < 4; ++fn) {
            const int px = wn * 64 + fn * 16 + pl;
            short8 bh = *(const short8*)&BH[(g * 128 + px) * 4];
            short8 bl = *(const short8*)&BL[(g * 128 + px) * 4];
            acc[0][fn] = mfma16(ah0, bh, acc[0][fn]);
            acc[1][fn] = mfma16(ah1, bh, acc[1][fn]);
            acc[0][fn] = mfma16(al0, bh, acc[0][fn]);
            acc[1][fn] = mfma16(al1, bh, acc[1][fn]);
            acc[0][fn] = mfma16(ah0, bl, acc[0][fn]);
            acc[1][fn] = mfma16(ah1, bl, acc[1][fn]);
        }
        __syncthreads();
    }
#pragma unroll
    for (int fm = 0; fm < 2; ++fm)
#pragma unroll
    for (int fn = 0; fn < 4; ++fn) {
        const int row = mt * 128 + (wm * 2 + fm) * 16 + (lane >> 4) * 4;
        const int j = j0 + wn * 64 + fn * 16 + (lane & 15);
        if (j >= NLM_N) continue;
        f32x4 a = acc[fm][fn];
#pragma unroll
        for (int r = 0; r < 4; ++r)
            S[((size_t)img * NLM_MAXM + row + r) * NLM_N + j] = a[r];
    }
}

// per-miss-row: D, dmin, w=exp, sumw; write w into A-fragment layout
__global__ __launch_bounds__(256) void nlm_row(
    const float* __restrict__ S, const float* __restrict__ sq,
    const float* __restrict__ nm2, const int* __restrict__ list,
    const int* __restrict__ cnt,
    short* __restrict__ W2hi, short* __restrict__ W2lo,
    float* __restrict__ sumw, float inv_h2) {
    const int img = blockIdx.y, i = blockIdx.x;
    if (i >= cnt[img] || i >= NLM_MAXM) return;
    __shared__ float Drow[NLM_N];
    __shared__ float red[256];
    const int tid = threadIdx.x;
    const int pix = list[img * NLM_MAXM + i];
    const float sqi = sq[img * NLM_N + pix];
    const float BIG = 3.4e38f;
    float lmin = BIG;
    for (int j = tid; j < NLM_N; j += 256) {
        float d = BIG;
        if (nm2[(size_t)img * NLM_N + j] != 0.f) {
            float dot = S[((size_t)img * NLM_MAXM + i) * NLM_N + j];
            d = sqi + sq[img * NLM_N + j] - 2.f * dot;
            d = d > 0.f ? d : 0.f;
            lmin = d < lmin ? d : lmin;
        }
        Drow[j] = d;
    }
    red[tid] = lmin;
    __syncthreads();
    for (int o = 128; o > 0; o >>= 1) {
        if (tid < o) red[tid] = fminf(red[tid], red[tid + o]);
        __syncthreads();
    }
    const float dmin = red[0];
    __syncthreads();

    const int rt = i >> 4, lr = i & 15;
    float lsum = 0.f;
    for (int j = tid; j < NLM_KB2 * 32; j += 256) {
        float w = 0.f;
        if (j < NLM_N && Drow[j] < 3.3e38f) {
            w = expf(-(Drow[j] - dmin) * inv_h2);
            lsum += w;
        }
        const unsigned u = splitpack(w);
        const int kb = j >> 5, kg = (j & 31) >> 3, jj = j & 7;
        const int lane = kg * 16 + lr;
        const size_t f = (size_t)img * NLM_WFRAG
                       + ((size_t)(kb * NLM_RT + rt) * 64 + lane) * 8 + jj;
        W2hi[f] = (short)(u & 0xFFFFu);
        W2lo[f] = (short)(u >> 16);
    }
    red[tid] = lsum;
    __syncthreads();
    for (int o = 128; o > 0; o >>= 1) {
        if (tid < o) red[tid] += red[tid + o];
        __syncthreads();
    }
    if (tid == 0) sumw[img * NLM_MAXM + i] = red[0];
}

// GEMM2: avg[i][c] = sum_j w[i][j] x[j][c] / sumw[i]; scatter to h2spair
__global__ __launch_bounds__(512) void nlm_gemm2(
    const unsigned* __restrict__ xTp, const short* __restrict__ W2hi,
    const short* __restrict__ W2lo, const int* __restrict__ cnt,
    const float* __restrict__ sumw, const int* __restrict__ list,
    unsigned* __restrict__ out) {
    const int img = blockIdx.z, mt = blockIdx.y, ct = blockIdx.x;
    const int cN = cnt[img] < NLM_MAXM ? cnt[img] : NLM_MAXM;
    if (mt * 128 >= cN) return;
    __shared__ __align__(16) unsigned BH[4 * 128 * 4];
    __shared__ __align__(16) unsigned BL[4 * 128 * 4];
    const int t = threadIdx.x, lane = t & 63, wv = t >> 6, wm = wv >> 1, wn = wv & 1;
    const int c0 = ct * 128;
    const int sc = t & 127, sg = t >> 7;
    f32x4 acc[2][4] = {};
#pragma unroll 1
    for (int kb = 0; kb < NLM_KB2; ++kb) {
        unsigned v[8];
#pragma unroll
        for (int jj = 0; jj < 8; ++jj) {
            const int j = kb * 32 + sg * 8 + jj;
            v[jj] = (j < NLM_N)
                  ? xTp[((size_t)img * NLM_N + j) * NLM_C + c0 + sc] : 0u;
        }
        uint4v hd, ld;
#pragma unroll
        for (int jj = 0; jj < 4; ++jj) {
            hd[jj] = (v[2 * jj] & 0xFFFFu) | (v[2 * jj + 1] << 16);
            ld[jj] = (v[2 * jj] >> 16) | (v[2 * jj + 1] & 0xFFFF0000u);
        }
        *(uint4v*)&BH[(sg * 128 + sc) * 4] = hd;
        *(uint4v*)&BL[(sg * 128 + sc) * 4] = ld;
        __syncthreads();
        const size_t ab = (size_t)img * NLM_WFRAG
                        + (size_t)(kb * NLM_RT + mt * 8 + wm * 2) * 512 + (size_t)lane * 8;
        short8 ah0 = *(const short8*)(W2hi + ab);
        short8 ah1 = *(const short8*)(W2hi + ab + 512);
        short8 al0 = *(const short8*)(W2lo + ab);
        short8 al1 = *(const short8*)(W2lo + ab + 512);
        const int g = lane >> 4, pl = lane & 15;
#pragma unroll
        for (int fn = 0; fn < 4; ++fn) {
            const int px = wn * 64 + fn * 16 + pl;
            short8 bh = *(const short8*)&BH[(g * 128 + px) * 4];
            short8 bl = *(const short8*)&BL[(g * 128 + px) * 4];
            acc[0][fn] = mfma16(ah0, bh, acc[0][fn]);
            acc[1][fn] = mfma16(ah1, bh, acc[1][fn]);
            acc[0][fn] = mfma16(al0, bh, acc[0][fn]);
            acc[1][fn] = mfma16(al1, bh, acc[1][fn]);
            acc[0][fn] = mfma16(ah0, bl, acc[0][fn]);
            acc[1][fn] = mfma16(ah1, bl, acc[1][fn]);
        }
        __syncthreads();
    }
#pragma unroll
    for (int fm = 0; fm < 2; ++fm)
#pragma unroll
    for (int fn = 0; fn < 4; ++fn) {
        const int row = mt * 128 + (wm * 2 + fm) * 16 + (lane >> 4) * 4;
        const int c = c0 + wn * 64 + fn * 16 + (lane & 15);
        f32x4 a = acc[fm][fn];
#pragma unroll
        for (int r = 0; r < 4; ++r) {
            const int ri = row + r;
            if (ri < cN) {
                const float y = a[r] / sumw[img * NLM_MAXM + ri];
                out[((size_t)img * NLM_C + c) * NLM_N + list[img * NLM_MAXM + ri]]
                    = splitpack(y);
            }
        }
    }
}

// ---------------------------------------------------------------------------
// Driver
// ---------------------------------------------------------------------------
extern "C" void kernel_launch(void* const* d_in, const int* in_sizes, int n_in,
                              void* d_out, int out_size, void* d_ws, size_t ws_size,
                              hipStream_t stream) {
    const float* x0    = (const float*)d_in[0];
    const float* m0    = (const float*)d_in[1];
    const float* Wsrc[8] = {
        (const float*)d_in[2], (const float*)d_in[3], (const float*)d_in[4],
        (const float*)d_in[5], (const float*)d_in[6], (const float*)d_in[7],
        (const float*)d_in[8], (const float*)d_in[9]
    };
    const float* dec1b = (const float*)d_in[10];
    const float* enc2g = (const float*)d_in[11];
    const float* enc2b = (const float*)d_in[12];
    const float* enc3g = (const float*)d_in[13];
    const float* enc3b = (const float*)d_in[14];
    const float* enc4g = (const float*)d_in[15];
    const float* enc4b = (const float*)d_in[16];
    const float* dec4g = (const float*)d_in[17];
    const float* dec4b = (const float*)d_in[18];
    const float* dec3g = (const float*)d_in[19];
    const float* dec3b = (const float*)d_in[20];
    const float* dec2g = (const float*)d_in[21];
    const float* dec2b = (const float*)d_in[22];
    float* outp = (float*)d_out;

    const int N = 8;
    float* ws = (float*)d_ws;
    size_t off = 0;
    auto alloc = [&](size_t nf) {
        size_t o = off;
        off += ((nf + 63) / 64) * 64;
        return ws + o;
    };

    unsigned* h1pair  = (unsigned*)alloc(10616832);  // 8x256x72x72  (later d2pair)
    unsigned* h2spair = (unsigned*)alloc(5308416);   // 8x512x36x36  (later d3pair)
    unsigned* h3pair  = (unsigned*)alloc(1327104);   // 8x512x18x18
    unsigned* h4pair  = (unsigned*)alloc(331776);    // 8x512x9x9
    unsigned* d4pair  = (unsigned*)alloc(1327104);
    float* ybuf = alloc(10616832);                   // pre-BN f32 scratch (max dec2)
    float* h2f  = alloc(5308416);                    // f32 h2 for NLM
    unsigned* xTp = (unsigned*)alloc(5308416);       // packed pair, [b][j][c]
    float* sqb  = alloc(10368);
    float* mc   = alloc(165888);
    float* nm1  = alloc(41472);
    float* nm2  = alloc(10368);
    float* nm3  = alloc(2592);
    float* nm4  = alloc(648);
    float* nmd4 = alloc(2592);
    float* nmd3 = alloc(10368);
    float* nmd2 = alloc(41472);
    float* nmx  = alloc(165888);
    float* bmean = alloc(512);
    float* bistd = alloc(512);
    short* Whi = (short*)alloc(10625024);            // 21,250,048 bf16
    short* Wlo = (short*)alloc(10625024);
    float* Smat = alloc((size_t)8 * NLM_MAXM * NLM_N);        // 2.65M f32
    short* Phi  = (short*)alloc((size_t)8 * NLM_PFRAG / 2);
    short* Plo  = (short*)alloc((size_t)8 * NLM_PFRAG / 2);
    short* W2hi = (short*)alloc((size_t)8 * NLM_WFRAG / 2);
    short* W2lo = (short*)alloc((size_t)8 * NLM_WFRAG / 2);
    int*   mlist = (int*)alloc(8 * NLM_MAXM);
    int*   mcnt  = (int*)alloc(64);
    float* sumw  = alloc(8 * NLM_MAXM);
    unsigned* d3pair = h2spair;
    unsigned* d2pair = h1pair;

    if (ws_size < off * sizeof(float)) return;

    auto cdiv = [](size_t a, size_t b) { return (int)((a + b - 1) / b); };

    // ---- weight transforms ----
    struct WLay { int Cout, Cin, K; size_t ofs; };
    const WLay WL[8] = {
        {256, 128, 7, 0},         // enc1
        {512, 256, 5, 1605632},   // enc2
        {512, 512, 3, 4882432},   // enc3
        {512, 512, 3, 7241728},   // enc4
        {512, 1024, 3, 9601024},  // dec4
        {512, 1024, 3, 14319616}, // dec3
        {256, 768, 3, 19038208},  // dec2
        {128, 384, 3, 20807680},  // dec1
    };
    for (int i = 0; i < 8; ++i) {
        size_t tot = (size_t)WL[i].Cout * WL[i].Cin * WL[i].K * WL[i].K;
        wtransform<<<cdiv(tot, 256), 256, 0, stream>>>(
            Wsrc[i], Whi + WL[i].ofs, Wlo + WL[i].ofs, WL[i].Cout, WL[i].Cin,
            WL[i].K * WL[i].K, tot);
    }

    // ---------------- enc1 ----------------
    maskconv_kernel<7, 2, false><<<cdiv(N * 72 * 72, 256), 256, 0, stream>>>(
        m0, 144, 144, mc, nm1, N, 144, 144, 72, 72);
    conv_enc<7, 2, 8, 8, 2, true, EPI_PAIR_RELU><<<dim3(81, 1, N), 512, 0, stream>>>(
        x0, 128, 144, 144, m0,
        Whi + WL[0].ofs, Wlo + WL[0].ofs, mc, nullptr, h1pair,
        72, 72, 256, 9);

    // ---------------- enc2 ----------------
    maskconv_kernel<5, 2, false><<<cdiv(N * 36 * 36, 256), 256, 0, stream>>>(
        nm1, 72, 72, mc, nm2, N, 72, 72, 36, 36);
    conv_enc<5, 2, 8, 8, 2, false, EPI_F32><<<dim3(25, 2, N), 512, 0, stream>>>(
        h1pair, 256, 72, 72, nm1,
        Whi + WL[1].ofs, Wlo + WL[1].ofs, mc, nullptr, ybuf,
        36, 36, 512, 5);
    bn_stats_kernel<<<512, 256, 0, stream>>>(ybuf, N, 512, 1296, bmean, bistd);
    bn_apply_pair<<<cdiv(5308416, 256), 256, 0, stream>>>(
        ybuf, bmean, bistd, enc2g, enc2b, h2spair, h2f, 512, 1296, 5308416, ACT_RELU);

    // ---------------- NLM swap (MFMA) ----------------
    nlm_trans<<<dim3(41, 16, N), 256, 0, stream>>>(h2f, xTp);
    nlm_sq2<<<dim3(6, N), 256, 0, stream>>>(h2f, sqb);
    hipMemsetAsync(mcnt, 0, 8 * sizeof(int), stream);
    nlm_compact<<<N, 256, 0, stream>>>(nm2, mlist, mcnt);
    nlm_gather<<<dim3(64, N), 256, 0, stream>>>(xTp, mlist, mcnt, Phi, Plo);
    nlm_gemm1<<<dim3(11, 2, N), 512, 0, stream>>>(xTp, Phi, Plo, mcnt, Smat);
    nlm_row<<<dim3(NLM_MAXM, N), 256, 0, stream>>>(Smat, sqb, nm2, mlist, mcnt,
                                                   W2hi, W2lo, sumw, 1.f / 25.f);
    nlm_gemm2<<<dim3(4, 2, N), 512, 0, stream>>>(xTp, W2hi, W2lo, mcnt, sumw,
                                                 mlist, h2spair);

    // ---------------- enc3 ----------------
    maskconv_kernel<3, 2, false><<<cdiv(N * 18 * 18, 256), 256, 0, stream>>>(
        nm2, 36, 36, mc, nm3, N, 36, 36, 18, 18);
    conv_enc<3, 2, 4, 8, 1, false, EPI_F32><<<dim3(15, 2, N), 512, 0, stream>>>(
        h2spair, 512, 36, 36, nm2,
        Whi + WL[2].ofs, Wlo + WL[2].ofs, mc, nullptr, ybuf,
        18, 18, 512, 3);
    bn_stats_kernel<<<512, 256, 0, stream>>>(ybuf, N, 512, 324, bmean, bistd);
    bn_apply_pair<<<cdiv(1327104, 256), 256, 0, stream>>>(
        ybuf, bmean, bistd, enc3g, enc3b, h3pair, nullptr, 512, 324, 1327104, ACT_RELU);

    // ---------------- enc4 ----------------
    maskconv_kernel<3, 2, false><<<cdiv(N * 9 * 9, 256), 256, 0, stream>>>(
        nm3, 18, 18, mc, nm4, N, 18, 18, 9, 9);
    conv_enc<3, 2, 4, 8, 1, false, EPI_F32><<<dim3(6, 2, N), 512, 0, stream>>>(
        h3pair, 512, 18, 18, nm3,
        Whi + WL[3].ofs, Wlo + WL[3].ofs, mc, nullptr, ybuf,
        9, 9, 512, 2);
    bn_stats_kernel<<<512, 256, 0, stream>>>(ybuf, N, 512, 81, bmean, bistd);
    bn_apply_pair<<<cdiv(331776, 256), 256, 0, stream>>>(
        ybuf, bmean, bistd, enc4g, enc4b, h4pair, nullptr, 512, 81, 331776, ACT_RELU);

    // ---------------- dec4 ----------------
    maskconv_kernel<3, 1, true><<<cdiv(N * 18 * 18, 256), 256, 0, stream>>>(
        nm4, 9, 9, mc, nmd4, N, 18, 18, 18, 18);
    conv3x3<9, 6, 4, false, EPI_F32><<<dim3(6, 4, N), 512, 0, stream>>>(
        h4pair, 512, 9, 9, h3pair, 512, nm4,
        Whi + WL[4].ofs, Wlo + WL[4].ofs, mc, nullptr, ybuf,
        18, 18, 512, 3);
    bn_stats_kernel<<<512, 256, 0, stream>>>(ybuf, N, 512, 324, bmean, bistd);
    bn_apply_pair<<<cdiv(1327104, 256), 256, 0, stream>>>(
        ybuf, bmean, bistd, dec4g, dec4b, d4pair, nullptr, 512, 324, 1327104, ACT_LEAKY);

    // ---------------- dec3 ----------------
    maskconv_kernel<3, 1, true><<<cdiv(N * 36 * 36, 256), 256, 0, stream>>>(
        nmd4, 18, 18, mc, nmd3, N, 36, 36, 36, 36);
    conv3x3<12, 8, 6, false, EPI_F32><<<dim3(15, 4, N), 512, 0, stream>>>(
        d4pair, 512, 18, 18, h2spair, 512, nmd4,
        Whi + WL[5].ofs, Wlo + WL[5].ofs, mc, nullptr, ybuf,
        36, 36, 512, 5);
    bn_stats_kernel<<<512, 256, 0, stream>>>(ybuf, N, 512, 1296, bmean, bistd);
    bn_apply_pair<<<cdiv(5308416, 256), 256, 0, stream>>>(
        ybuf, bmean, bistd, dec3g, dec3b, d3pair, nullptr, 512, 1296, 5308416, ACT_LEAKY);

    // ---------------- dec2 ----------------
    maskconv_kernel<3, 1, true><<<cdiv(N * 72 * 72, 256), 256, 0, stream>>>(
        nmd3, 36, 36, mc, nmd2, N, 72, 72, 72, 72);
    conv3x3<8, 12, 6, false, EPI_F32><<<dim3(54, 2, N), 512, 0, stream>>>(
        d3pair, 512, 36, 36, h1pair, 256, nmd3,
        Whi + WL[6].ofs, Wlo + WL[6].ofs, mc, nullptr, ybuf,
        72, 72, 256, 6);
    bn_stats_kernel<<<256, 256, 0, stream>>>(ybuf, N, 256, 5184, bmean, bistd);
    bn_apply_pair<<<cdiv(10616832, 256), 256, 0, stream>>>(
        ybuf, bmean, bistd, dec2g, dec2b, d2pair, nullptr, 256, 5184, 10616832, ACT_LEAKY);

    // ---------------- dec1 ----------------
    maskconv_kernel<3, 1, true><<<cdiv(N * 144 * 144, 256), 256, 0, stream>>>(
        nmd2, 72, 72, mc, nmx, N, 144, 144, 144, 144);
    conv3x3<16, 16, 16, true, EPI_F32_BIAS><<<dim3(81, 1, N), 512, 0, stream>>>(
        d2pair, 256, 72, 72, x0, 128, nmd2,
        Whi + WL[7].ofs, Wlo + WL[7].ofs, mc, dec1b, outp,
        144, 144, 128, 9);
}